// Round 1
// baseline (3311.366 us; speedup 1.0000x reference)
//
#include <hip/hip_runtime.h>
#include <math.h>
#include <stdint.h>

// GCNModelVAE forward on MI355X — round 0 baseline.
// N=2048, F_IN=768, H1=512, H2=256, LC=256, HEADS=2, MAX_K=512.

namespace {

constexpr int NN   = 2048;
constexpr int FIN  = 768;
constexpr int H1D  = 512;
constexpr int H2D  = 256;
constexpr int LCD  = 256;
constexpr int TOPK = 512;
constexpr int TOTE = NN * NN;          // 4194304, fits int

struct SelState {
  unsigned hist[256];
  unsigned prefix, remaining, T, r;     // value select
  unsigned iprefix, iremaining, Ithr;   // index select (ties)
  unsigned cTotal;
  double sum1, sum0, labSum, kldSum;    // reductions
};

__device__ __forceinline__ float logsig(float x) {
  // jax.nn.log_sigmoid, numerically stable
  if (x >= 0.f) return -log1pf(expf(-x));
  return x - log1pf(expf(x));
}

// ---------------- generic tiled fp32 GEMM ----------------
// C[M,N] = act(scale * A @ op(B)) ; A row-major [M,lda]
// TRANSB=0: B[k*ldb+n]; TRANSB=1: B[n*ldb+k]
// ACT: 0=none 1=leaky(0.01) 2=sigmoid. Batched via blockIdx.z (element strides).
template<int ACT, int TRANSB>
__global__ __launch_bounds__(256)
void gemm_kernel(const float* __restrict__ A, const float* __restrict__ B,
                 float* __restrict__ C, int M, int N, int K,
                 int lda, int ldb, int ldc, float scale,
                 long long bsA, long long bsB, long long bsC)
{
  constexpr int TM = 32, TN = 64, KT = 16;
  __shared__ float As[KT][TM + 4];
  __shared__ float Bs[KT][TN + 4];
  A += bsA * blockIdx.z; B += bsB * blockIdx.z; C += bsC * blockIdx.z;
  const int t  = threadIdx.x;
  const int tx = t & 15, ty = t >> 4;          // 16 x 16
  const int bm = blockIdx.y * TM, bn = blockIdx.x * TN;
  float acc[2][4] = {};
  for (int k0 = 0; k0 < K; k0 += KT) {
    #pragma unroll
    for (int i = 0; i < 2; ++i) {              // A tile: 32x16 = 512 elems
      int idx = t + i * 256;
      int kk = idx & 15, m = idx >> 4;
      int gm = bm + m, gk = k0 + kk;
      As[kk][m] = (gm < M && gk < K) ? A[(long long)gm * lda + gk] : 0.f;
    }
    #pragma unroll
    for (int i = 0; i < 4; ++i) {              // B tile: 16x64 = 1024 elems
      int idx = t + i * 256;
      int n, kk;
      if (TRANSB) { kk = idx & 15; n = idx >> 4; }
      else        { n = idx & 63;  kk = idx >> 6; }
      int gn = bn + n, gk = k0 + kk;
      float v = 0.f;
      if (gn < N && gk < K)
        v = TRANSB ? B[(long long)gn * ldb + gk] : B[(long long)gk * ldb + gn];
      Bs[kk][n] = v;
    }
    __syncthreads();
    #pragma unroll
    for (int kk = 0; kk < KT; ++kk) {
      float a0 = As[kk][ty * 2 + 0], a1 = As[kk][ty * 2 + 1];
      float b0 = Bs[kk][tx * 4 + 0], b1 = Bs[kk][tx * 4 + 1];
      float b2 = Bs[kk][tx * 4 + 2], b3 = Bs[kk][tx * 4 + 3];
      acc[0][0] += a0 * b0; acc[0][1] += a0 * b1; acc[0][2] += a0 * b2; acc[0][3] += a0 * b3;
      acc[1][0] += a1 * b0; acc[1][1] += a1 * b1; acc[1][2] += a1 * b2; acc[1][3] += a1 * b3;
    }
    __syncthreads();
  }
  #pragma unroll
  for (int i = 0; i < 2; ++i) {
    int gm = bm + ty * 2 + i;
    if (gm >= M) continue;
    #pragma unroll
    for (int j = 0; j < 4; ++j) {
      int gn = bn + tx * 4 + j;
      if (gn >= N) continue;
      float v = acc[i][j] * scale;
      if (ACT == 1)      v = (v >= 0.f) ? v : 0.01f * v;
      else if (ACT == 2) v = 1.f / (1.f + expf(-v));
      C[(long long)gm * ldc + gn] = v;
    }
  }
}

// ---------------- softmax over rows of length 256 ----------------
__global__ __launch_bounds__(256)
void softmax256(float* __restrict__ x)
{
  __shared__ float red[256];
  const int row = blockIdx.x, t = threadIdx.x;
  float v = x[row * 256 + t];
  red[t] = v; __syncthreads();
  for (int s = 128; s > 0; s >>= 1) { if (t < s) red[t] = fmaxf(red[t], red[t + s]); __syncthreads(); }
  float m = red[0]; __syncthreads();
  float e = expf(v - m);
  red[t] = e; __syncthreads();
  for (int s = 128; s > 0; s >>= 1) { if (t < s) red[t] += red[t + s]; __syncthreads(); }
  x[row * 256 + t] = e / red[0];
}

// ---------------- z = eps * exp(0.5*lv) + mu  (mu|lv packed [N,512]) ----------------
__global__ __launch_bounds__(256)
void z_kernel(const float* __restrict__ eps, const float* __restrict__ mulv,
              float* __restrict__ z)
{
  int idx = blockIdx.x * 256 + threadIdx.x;   // < NN*H2D
  int r = idx >> 8, c = idx & 255;
  float mu = mulv[r * 512 + c];
  float lv = mulv[r * 512 + 256 + c];
  z[idx] = eps[idx] * expf(0.5f * lv) + mu;
}

// ---------------- BCE partial sums + label sum ----------------
__global__ __launch_bounds__(256)
void bce_kernel(const float* __restrict__ radj, const float* __restrict__ labels,
                SelState* st)
{
  int idx = blockIdx.x * 256 + threadIdx.x;   // grid covers NN*NN exactly
  float p = radj[idx], lb = labels[idx];
  float s1 = lb * (-logsig(p));
  float s0 = (1.f - lb) * (-logsig(-p));
  __shared__ float r1[256], r0[256], rl[256];
  r1[threadIdx.x] = s1; r0[threadIdx.x] = s0; rl[threadIdx.x] = lb;
  __syncthreads();
  for (int s = 128; s > 0; s >>= 1) {
    if (threadIdx.x < s) {
      r1[threadIdx.x] += r1[threadIdx.x + s];
      r0[threadIdx.x] += r0[threadIdx.x + s];
      rl[threadIdx.x] += rl[threadIdx.x + s];
    }
    __syncthreads();
  }
  if (threadIdx.x == 0) {
    atomicAdd(&st->sum1,  (double)r1[0]);
    atomicAdd(&st->sum0,  (double)r0[0]);
    atomicAdd(&st->labSum,(double)rl[0]);
  }
}

// ---------------- KLD partial sum ----------------
__global__ __launch_bounds__(256)
void kld_kernel(const float* __restrict__ mpo, const float* __restrict__ mpr,
                SelState* st)
{
  int idx = blockIdx.x * 256 + threadIdx.x;   // < NN*H2D
  int r = idx >> 8, c = idx & 255;
  float mu_po = mpo[r * 512 + c], lv_po = mpo[r * 512 + 256 + c];
  float mu_pr = mpr[r * 512 + c], lv_pr = mpr[r * 512 + 256 + c];
  float d = mu_pr - mu_po, dl = lv_po - lv_pr;
  float term = d * d * expf(-lv_pr) + expf(dl) - 1.f - dl;
  __shared__ float red[256];
  red[threadIdx.x] = term; __syncthreads();
  for (int s = 128; s > 0; s >>= 1) {
    if (threadIdx.x < s) red[threadIdx.x] += red[threadIdx.x + s];
    __syncthreads();
  }
  if (threadIdx.x == 0) atomicAdd(&st->kldSum, (double)red[0]);
}

// ---------------- exact top-512 radix select over triu(radj) ----------------
__global__ __launch_bounds__(256)
void radix_count_val(const float* __restrict__ radj, SelState* st,
                     int shift, unsigned mask)
{
  __shared__ unsigned h[256];
  h[threadIdx.x] = 0; __syncthreads();
  const unsigned pref = st->prefix & mask;
  for (int idx = blockIdx.x * 256 + threadIdx.x; idx < TOTE; idx += gridDim.x * 256) {
    int i = idx >> 11, j = idx & 2047;
    if (j <= i) continue;                      // strictly upper triangle
    unsigned b = __float_as_uint(radj[idx]);   // all values in (0,1]: uint order = float order
    if ((b & mask) == pref) atomicAdd(&h[(b >> shift) & 255], 1u);
  }
  __syncthreads();
  if (h[threadIdx.x]) atomicAdd(&st->hist[threadIdx.x], h[threadIdx.x]);
}

__global__ void scan_val(SelState* st, int shift, int pass, unsigned k)
{
  unsigned rem = (pass == 0) ? k : st->remaining;
  unsigned cg = 0;
  for (int b = 255; b >= 0; --b) {
    unsigned c = st->hist[b];
    if (cg + c >= rem) { st->prefix |= ((unsigned)b) << shift; st->remaining = rem - cg; break; }
    cg += c;
  }
  for (int b = 0; b < 256; ++b) st->hist[b] = 0;
  if (pass == 3) { st->T = st->prefix; st->r = st->remaining; }
}

__global__ __launch_bounds__(256)
void radix_count_idx(const float* __restrict__ radj, SelState* st,
                     int shift, unsigned mask)
{
  __shared__ unsigned h[256];
  h[threadIdx.x] = 0; __syncthreads();
  const unsigned T = st->T;
  const unsigned pref = st->iprefix & mask;
  for (int idx = blockIdx.x * 256 + threadIdx.x; idx < TOTE; idx += gridDim.x * 256) {
    int i = idx >> 11, j = idx & 2047;
    if (j <= i) continue;
    unsigned b = __float_as_uint(radj[idx]);
    if (b != T) continue;
    unsigned u = (unsigned)idx;
    if ((u & mask) == pref) atomicAdd(&h[(u >> shift) & 255], 1u);
  }
  __syncthreads();
  if (h[threadIdx.x]) atomicAdd(&st->hist[threadIdx.x], h[threadIdx.x]);
}

__global__ void scan_idx(SelState* st, int shift, int pass)
{
  unsigned rem = (pass == 0) ? st->r : st->iremaining;
  unsigned cl = 0;
  for (int b = 0; b < 256; ++b) {            // ascending: smallest indices win ties (JAX stable)
    unsigned c = st->hist[b];
    if (cl + c >= rem) { st->iprefix |= ((unsigned)b) << shift; st->iremaining = rem - cl; break; }
    cl += c;
  }
  for (int b = 0; b < 256; ++b) st->hist[b] = 0;
  if (pass == 3) st->Ithr = st->iprefix;
}

__global__ __launch_bounds__(256)
void collect_kernel(const float* __restrict__ radj, SelState* st,
                    unsigned* __restrict__ cand_bits, unsigned* __restrict__ cand_idx)
{
  const unsigned T = st->T, It = st->Ithr;
  for (int idx = blockIdx.x * 256 + threadIdx.x; idx < TOTE; idx += gridDim.x * 256) {
    int i = idx >> 11, j = idx & 2047;
    if (j <= i) continue;
    unsigned b = __float_as_uint(radj[idx]);
    if (b > T || (b == T && (unsigned)idx <= It)) {
      unsigned p = atomicAdd(&st->cTotal, 1u);
      if (p < (unsigned)TOPK) { cand_bits[p] = b; cand_idx[p] = (unsigned)idx; }
    }
  }
}

__global__ __launch_bounds__(512)
void rank_sort(const unsigned* __restrict__ cand_bits,
               const unsigned* __restrict__ cand_idx, unsigned* __restrict__ ord)
{
  __shared__ unsigned vb[512], vi[512];
  int t = threadIdx.x;
  vb[t] = cand_bits[t]; vi[t] = cand_idx[t];
  __syncthreads();
  unsigned b = vb[t], id = vi[t];
  int rank = 0;
  for (int u = 0; u < 512; ++u)
    rank += (vb[u] > b) || (vb[u] == b && vi[u] < id);   // value desc, idx asc (stable)
  ord[rank] = id;
}

__global__ __launch_bounds__(256)
void gather_rel(const unsigned* __restrict__ ord, const float* __restrict__ ns2,
                float* __restrict__ out)
{
  int r = blockIdx.x, c = threadIdx.x;
  unsigned id = ord[r];
  int a = id >> 11, b = id & 2047;
  out[r * 256 + c] = ns2[a * 256 + c] + ns2[b * 256 + c];
}

__global__ __launch_bounds__(512)
void finalize_kernel(const SelState* st, float* __restrict__ out)
{
  int t = threadIdx.x;
  out[TOPK * H2D + t] = 0.0f;                 // rel_mask: all False (rel_num >> MAX_K)
  if (t == 0) {
    double s   = st->labSum;
    double nn  = (double)NN * NN;
    double pw  = (nn - s + NN) / (s - NN + 0.01);
    double nrm = nn / (nn - s + NN);
    out[TOPK * H2D + TOPK + 0] = (float)(nrm * (pw * st->sum1 + st->sum0) / nn);
    out[TOPK * H2D + TOPK + 1] = (float)(0.5 * st->kldSum / nn);
  }
}

void launch_gemm(hipStream_t stream, int act, int transb,
                 const float* A, const float* B, float* C,
                 int M, int Nc, int K, int lda, int ldb, int ldc, float scale,
                 int batch = 1, long long bsA = 0, long long bsB = 0, long long bsC = 0)
{
  dim3 g((Nc + 63) / 64, (M + 31) / 32, batch), blk(256);
  if (!transb) {
    if (act == 0)      gemm_kernel<0,0><<<g,blk,0,stream>>>(A,B,C,M,Nc,K,lda,ldb,ldc,scale,bsA,bsB,bsC);
    else if (act == 1) gemm_kernel<1,0><<<g,blk,0,stream>>>(A,B,C,M,Nc,K,lda,ldb,ldc,scale,bsA,bsB,bsC);
    else               gemm_kernel<2,0><<<g,blk,0,stream>>>(A,B,C,M,Nc,K,lda,ldb,ldc,scale,bsA,bsB,bsC);
  } else {
    if (act == 0)      gemm_kernel<0,1><<<g,blk,0,stream>>>(A,B,C,M,Nc,K,lda,ldb,ldc,scale,bsA,bsB,bsC);
    else if (act == 1) gemm_kernel<1,1><<<g,blk,0,stream>>>(A,B,C,M,Nc,K,lda,ldb,ldc,scale,bsA,bsB,bsC);
    else               gemm_kernel<2,1><<<g,blk,0,stream>>>(A,B,C,M,Nc,K,lda,ldb,ldc,scale,bsA,bsB,bsC);
  }
}

} // namespace

extern "C" void kernel_launch(void* const* d_in, const int* in_sizes, int n_in,
                              void* d_out, int out_size, void* d_ws, size_t ws_size,
                              hipStream_t stream)
{
  (void)in_sizes; (void)n_in; (void)out_size; (void)ws_size;
  const float* ns_emb    = (const float*)d_in[0];
  const float* adj       = (const float*)d_in[1];
  const float* adj_prior = (const float*)d_in[2];
  const float* cond      = (const float*)d_in[3];   // [1,256,768] -> [256,768]
  const float* labels    = (const float*)d_in[4];
  const float* eps       = (const float*)d_in[5];
  const float* W_map     = (const float*)d_in[6];
  const float* Wb[2][7];
  for (int br = 0; br < 7 * 2; ++br) Wb[br / 7][br % 7] = (const float*)d_in[7 + br];
  // per branch: W_hid, Wq, Wk, Wv, Wo, W_mu, W_var

  float* out = (float*)d_out;

  // ---- workspace carve ----
  char* w = (char*)d_ws;
  SelState* st = (SelState*)w;               w += 2048;
  unsigned* cand_bits = (unsigned*)w;        w += TOPK * 4;
  unsigned* cand_idx  = (unsigned*)w;        w += TOPK * 4;
  unsigned* ord       = (unsigned*)w;        w += TOPK * 4;
  w = (char*)(((uintptr_t)w + 255) & ~(uintptr_t)255);
  float* bufS  = (float*)w;  w += (size_t)NN * H1D * 4;
  float* bufH  = (float*)w;  w += (size_t)NN * H1D * 4;
  float* bufQ  = (float*)w;  w += (size_t)NN * H1D * 4;
  float* bufO  = (float*)w;  w += (size_t)NN * H1D * 4;
  float* bufSC = (float*)w;  w += (size_t)2 * NN * 256 * 4;
  float* bufK  = (float*)w;  w += (size_t)LCD * H1D * 4;
  float* bufV  = (float*)w;  w += (size_t)LCD * H1D * 4;
  float* bufT2 = (float*)w;  w += (size_t)NN * H1D * 4;
  float* mulv[2];
  mulv[0] = (float*)w;       w += (size_t)NN * H1D * 4;   // [mu_post | lv_post]  [N,512]
  mulv[1] = (float*)w;       w += (size_t)NN * H1D * 4;   // [mu_prior| lv_prior]
  float* zb   = (float*)w;   w += (size_t)NN * H2D * 4;
  float* ns2  = (float*)w;   w += (size_t)NN * H2D * 4;
  float* radj = (float*)w;   w += (size_t)NN * NN * 4;

  hipMemsetAsync(st, 0, sizeof(SelState), stream);

  // ---- two encoder branches (post uses adj, prior uses adj_prior) ----
  for (int br = 0; br < 2; ++br) {
    const float* A_adj = br ? adj_prior : adj;
    const float *W_hid = Wb[br][0], *Wq = Wb[br][1], *Wk = Wb[br][2],
                *Wv = Wb[br][3], *Wo = Wb[br][4], *W_mu = Wb[br][5], *W_var = Wb[br][6];

    // gcn1: S = leaky(ns_emb @ W_hid); Hg = leaky(adj @ S)
    launch_gemm(stream, 1, 0, ns_emb, W_hid, bufS, NN, H1D, FIN, FIN, H1D, H1D, 1.f);
    launch_gemm(stream, 1, 0, A_adj,  bufS,  bufH, NN, H1D, NN,  NN,  H1D, H1D, 1.f);
    // mha projections
    launch_gemm(stream, 0, 0, bufH, Wq, bufQ, NN,  H1D, H1D, H1D, H1D, H1D, 1.f);
    launch_gemm(stream, 0, 0, cond, Wk, bufK, LCD, H1D, FIN, FIN, H1D, H1D, 1.f);
    launch_gemm(stream, 0, 0, cond, Wv, bufV, LCD, H1D, FIN, FIN, H1D, H1D, 1.f);
    // scores (batched over 2 heads, B transposed), softmax, attn @ V
    launch_gemm(stream, 0, 1, bufQ, bufK, bufSC, NN, LCD, 256, H1D, H1D, 256, 0.0625f,
                2, 256, 256, (long long)NN * 256);
    softmax256<<<dim3(2 * NN), dim3(256), 0, stream>>>(bufSC);
    launch_gemm(stream, 0, 0, bufSC, bufV, bufO, NN, 256, LCD, 256, H1D, H1D, 1.f,
                2, (long long)NN * 256, 256, 256);
    // o @ Wo -> new hidden
    launch_gemm(stream, 0, 0, bufO, Wo, bufH, NN, H1D, H1D, H1D, H1D, H1D, 1.f);
    // mu/var: s2 = leaky(H @ W_mu|W_var) packed [N,512]; mu|lv = leaky(adj @ s2)
    launch_gemm(stream, 1, 0, bufH, W_mu,  bufT2,       NN, H2D, H1D, H1D, H2D, H1D, 1.f);
    launch_gemm(stream, 1, 0, bufH, W_var, bufT2 + H2D, NN, H2D, H1D, H1D, H2D, H1D, 1.f);
    launch_gemm(stream, 1, 0, A_adj, bufT2, mulv[br],   NN, H1D, NN,  NN,  H1D, H1D, 1.f);
  }

  // ---- decoder + losses ----
  z_kernel<<<dim3(NN), dim3(256), 0, stream>>>(eps, mulv[0], zb);
  launch_gemm(stream, 2, 1, zb, zb, radj, NN, NN, H2D, H2D, H2D, NN, 1.f);   // sigmoid(z @ z^T)
  launch_gemm(stream, 1, 0, ns_emb, W_map, ns2, NN, H2D, FIN, FIN, H2D, H2D, 1.f);

  bce_kernel<<<dim3(TOTE / 256), dim3(256), 0, stream>>>(radj, labels, st);
  kld_kernel<<<dim3(NN * H2D / 256), dim3(256), 0, stream>>>(mulv[0], mulv[1], st);

  // ---- exact top-512 of triu(radj): radix select on value bits, then index (ties) ----
  const unsigned masks[4] = {0u, 0xFF000000u, 0xFFFF0000u, 0xFFFFFF00u};
  for (int pass = 0; pass < 4; ++pass) {
    int shift = 24 - 8 * pass;
    radix_count_val<<<dim3(1024), dim3(256), 0, stream>>>(radj, st, shift, masks[pass]);
    scan_val<<<dim3(1), dim3(1), 0, stream>>>(st, shift, pass, TOPK);
  }
  for (int pass = 0; pass < 4; ++pass) {
    int shift = 24 - 8 * pass;
    radix_count_idx<<<dim3(1024), dim3(256), 0, stream>>>(radj, st, shift, masks[pass]);
    scan_idx<<<dim3(1), dim3(1), 0, stream>>>(st, shift, pass);
  }
  collect_kernel<<<dim3(1024), dim3(256), 0, stream>>>(radj, st, cand_bits, cand_idx);
  rank_sort<<<dim3(1), dim3(512), 0, stream>>>(cand_bits, cand_idx, ord);
  gather_rel<<<dim3(TOPK), dim3(256), 0, stream>>>(ord, ns2, out);
  finalize_kernel<<<dim3(1), dim3(512), 0, stream>>>(st, out);
}

// Round 2
// 1249.425 us; speedup vs baseline: 2.6503x; 2.6503x over previous
//
#include <hip/hip_runtime.h>
#include <math.h>
#include <stdint.h>

// GCNModelVAE forward on MI355X — round 1.
// Changes vs round 0:
//  - bce/kld: grid-stride + few blocks (atomic serialization was 598us -> ~20us)
//  - adj @ X via on-the-fly ELL sparse (adj is 99% sparse) instead of dense GEMM
//  - dense GEMM: 64x64 tile, 4x4 micro-tile, float4 LDS frags, no bounds checks
//  - z@zT symmetric: upper-triangle blocks only, mirrored store
//  - radix select scans iterate upper triangle only (row-based)

namespace {

constexpr int NN   = 2048;
constexpr int FIN  = 768;
constexpr int H1D  = 512;
constexpr int H2D  = 256;
constexpr int LCD  = 256;
constexpr int TOPK = 512;
constexpr int TOTE = NN * NN;
constexpr int CAP  = 96;               // ELL max nnz/row (row mean ~20.5, +9sigma safe)

struct SelState {
  unsigned hist[256];
  unsigned prefix, remaining, T, r;
  unsigned iprefix, iremaining, Ithr;
  unsigned cTotal;
  double sum1, sum0, labSum, kldSum;
};

__device__ __forceinline__ float logsig(float x) {
  if (x >= 0.f) return -log1pf(expf(-x));
  return x - log1pf(expf(x));
}
__device__ __forceinline__ float leaky(float v) { return v >= 0.f ? v : 0.01f * v; }

// ---------------- dense fp32 GEMM: 64x64 tile, 4x4 micro ----------------
// Requires M%64==0, N%64==0, K%16==0, lda/ldb/ldc%4==0 (all true here).
// TRANSB=0: B[k*ldb+n]; TRANSB=1: B[n*ldb+k].
// ACT: 0 none, 1 leaky, 2 sigmoid. SYMU: A@A^T upper blocks + mirrored store.
template<int ACT, int TRANSB, int SYMU>
__global__ __launch_bounds__(256)
void gemm64(const float* __restrict__ A, const float* __restrict__ B,
            float* __restrict__ C, int M, int N, int K,
            int lda, int ldb, int ldc, float scale,
            long long bsA, long long bsB, long long bsC)
{
  if (SYMU && (int)blockIdx.x < (int)blockIdx.y) return;
  constexpr int KT = 16;
  __shared__ float As[KT][64 + 4];
  __shared__ float Bs[KT][64 + 4];
  A += bsA * blockIdx.z; B += bsB * blockIdx.z; C += bsC * blockIdx.z;
  const int t  = threadIdx.x;
  const int bm = blockIdx.y * 64, bn = blockIdx.x * 64;
  const int lr = t >> 2, lq = t & 3;       // A / B-trans staging: 64 rows x 4 k-quads
  const int bkr = t >> 4, bnq = t & 15;    // B-notrans staging: 16 k x 16 n-quads
  const int tx = t & 15, ty = t >> 4;
  float acc[4][4] = {};
  const float* Aptr = A + (long long)(bm + lr) * lda + lq * 4;
  const float* Bptr = TRANSB ? (B + (long long)(bn + lr) * ldb + lq * 4)
                             : (B + (long long)bkr * ldb + bn + bnq * 4);
  for (int k0 = 0; k0 < K; k0 += KT) {
    float4 av = *(const float4*)(Aptr + k0);
    As[lq * 4 + 0][lr] = av.x; As[lq * 4 + 1][lr] = av.y;
    As[lq * 4 + 2][lr] = av.z; As[lq * 4 + 3][lr] = av.w;
    if (TRANSB) {
      float4 bv = *(const float4*)(Bptr + k0);
      Bs[lq * 4 + 0][lr] = bv.x; Bs[lq * 4 + 1][lr] = bv.y;
      Bs[lq * 4 + 2][lr] = bv.z; Bs[lq * 4 + 3][lr] = bv.w;
    } else {
      float4 bv = *(const float4*)(Bptr + (long long)k0 * ldb);
      *(float4*)&Bs[bkr][bnq * 4] = bv;
    }
    __syncthreads();
    #pragma unroll
    for (int kk = 0; kk < KT; ++kk) {
      float4 a = *(const float4*)&As[kk][ty * 4];
      float4 b = *(const float4*)&Bs[kk][tx * 4];
      acc[0][0] += a.x * b.x; acc[0][1] += a.x * b.y; acc[0][2] += a.x * b.z; acc[0][3] += a.x * b.w;
      acc[1][0] += a.y * b.x; acc[1][1] += a.y * b.y; acc[1][2] += a.y * b.z; acc[1][3] += a.y * b.w;
      acc[2][0] += a.z * b.x; acc[2][1] += a.z * b.y; acc[2][2] += a.z * b.z; acc[2][3] += a.z * b.w;
      acc[3][0] += a.w * b.x; acc[3][1] += a.w * b.y; acc[3][2] += a.w * b.z; acc[3][3] += a.w * b.w;
    }
    __syncthreads();
  }
  float o[4][4];
  #pragma unroll
  for (int i = 0; i < 4; ++i)
    #pragma unroll
    for (int j = 0; j < 4; ++j) {
      float v = acc[i][j] * scale;
      if (ACT == 1)      v = leaky(v);
      else if (ACT == 2) v = 1.f / (1.f + expf(-v));
      o[i][j] = v;
    }
  #pragma unroll
  for (int i = 0; i < 4; ++i) {
    float4 st = make_float4(o[i][0], o[i][1], o[i][2], o[i][3]);
    *(float4*)&C[(long long)(bm + ty * 4 + i) * ldc + bn + tx * 4] = st;
  }
  if (SYMU) {
    #pragma unroll
    for (int j = 0; j < 4; ++j) {
      float4 st = make_float4(o[0][j], o[1][j], o[2][j], o[3][j]);
      *(float4*)&C[(long long)(bn + tx * 4 + j) * ldc + bm + ty * 4] = st;
    }
  }
}

// ---------------- ELL build: one wave per row, ordered compaction ----------------
__global__ __launch_bounds__(64)
void build_ell(const float* __restrict__ adj, int* __restrict__ cnt,
               int* __restrict__ cols, float* __restrict__ vals)
{
  const int row = blockIdx.x, lane = threadIdx.x;
  int base = 0;
  for (int c0 = 0; c0 < NN; c0 += 64) {
    float v = adj[(long long)row * NN + c0 + lane];
    unsigned long long m = __ballot(v != 0.0f);
    if (v != 0.0f) {
      int pos = base + __popcll(m & ((1ull << lane) - 1ull));
      if (pos < CAP) { cols[row * CAP + pos] = c0 + lane; vals[row * CAP + pos] = v; }
    }
    base += __popcll(m);
  }
  if (lane == 0) cnt[row] = base > CAP ? CAP : base;
}

// ---------------- out[row] = leaky(sum_i val_i * S[col_i]) ; Ncols = 512 ----------------
__global__ __launch_bounds__(256)
void spmm_leaky(const int* __restrict__ cnt, const int* __restrict__ cols,
                const float* __restrict__ vals, const float* __restrict__ S,
                float* __restrict__ out)
{
  const int row = blockIdx.x, t = threadIdx.x;
  __shared__ int   sc[CAP];
  __shared__ float sv[CAP];
  __shared__ int   n;
  if (t == 0) n = cnt[row];
  if (t < CAP) { sc[t] = cols[row * CAP + t]; sv[t] = vals[row * CAP + t]; }
  __syncthreads();
  const int m = n;
  float a0 = 0.f, a1 = 0.f;
  for (int i = 0; i < m; ++i) {
    const float* Sr = S + (long long)sc[i] * 512;
    float v = sv[i];
    a0 += v * Sr[t];
    a1 += v * Sr[t + 256];
  }
  out[(long long)row * 512 + t]       = leaky(a0);
  out[(long long)row * 512 + t + 256] = leaky(a1);
}

// ---------------- softmax over rows of length 256 ----------------
__global__ __launch_bounds__(256)
void softmax256(float* __restrict__ x)
{
  __shared__ float red[256];
  const int row = blockIdx.x, t = threadIdx.x;
  float v = x[(long long)row * 256 + t];
  red[t] = v; __syncthreads();
  for (int s = 128; s > 0; s >>= 1) { if (t < s) red[t] = fmaxf(red[t], red[t + s]); __syncthreads(); }
  float m = red[0]; __syncthreads();
  float e = expf(v - m);
  red[t] = e; __syncthreads();
  for (int s = 128; s > 0; s >>= 1) { if (t < s) red[t] += red[t + s]; __syncthreads(); }
  x[(long long)row * 256 + t] = e / red[0];
}

// ---------------- z = eps * exp(0.5*lv) + mu ----------------
__global__ __launch_bounds__(256)
void z_kernel(const float* __restrict__ eps, const float* __restrict__ mulv,
              float* __restrict__ z)
{
  int idx = blockIdx.x * 256 + threadIdx.x;
  int r = idx >> 8, c = idx & 255;
  float mu = mulv[r * 512 + c];
  float lv = mulv[r * 512 + 256 + c];
  z[idx] = eps[idx] * expf(0.5f * lv) + mu;
}

// ---------------- BCE partials (grid-stride, 512 blocks) ----------------
__global__ __launch_bounds__(256)
void bce_kernel(const float* __restrict__ radj, const float* __restrict__ labels,
                SelState* st)
{
  float s1 = 0.f, s0 = 0.f, sl = 0.f;
  for (int idx = blockIdx.x * 256 + threadIdx.x; idx < TOTE; idx += 512 * 256) {
    float p = radj[idx], lb = labels[idx];
    s1 += lb * (-logsig(p));
    s0 += (1.f - lb) * (-logsig(-p));
    sl += lb;
  }
  __shared__ float r1[256], r0[256], rl[256];
  r1[threadIdx.x] = s1; r0[threadIdx.x] = s0; rl[threadIdx.x] = sl;
  __syncthreads();
  for (int s = 128; s > 0; s >>= 1) {
    if (threadIdx.x < s) {
      r1[threadIdx.x] += r1[threadIdx.x + s];
      r0[threadIdx.x] += r0[threadIdx.x + s];
      rl[threadIdx.x] += rl[threadIdx.x + s];
    }
    __syncthreads();
  }
  if (threadIdx.x == 0) {
    atomicAdd(&st->sum1,   (double)r1[0]);
    atomicAdd(&st->sum0,   (double)r0[0]);
    atomicAdd(&st->labSum, (double)rl[0]);
  }
}

// ---------------- KLD partials (grid-stride, 256 blocks) ----------------
__global__ __launch_bounds__(256)
void kld_kernel(const float* __restrict__ mpo, const float* __restrict__ mpr,
                SelState* st)
{
  float acc = 0.f;
  for (int idx = blockIdx.x * 256 + threadIdx.x; idx < NN * H2D; idx += 256 * 256) {
    int r = idx >> 8, c = idx & 255;
    float mu_po = mpo[r * 512 + c], lv_po = mpo[r * 512 + 256 + c];
    float mu_pr = mpr[r * 512 + c], lv_pr = mpr[r * 512 + 256 + c];
    float d = mu_pr - mu_po, dl = lv_po - lv_pr;
    acc += d * d * expf(-lv_pr) + expf(dl) - 1.f - dl;
  }
  __shared__ float red[256];
  red[threadIdx.x] = acc; __syncthreads();
  for (int s = 128; s > 0; s >>= 1) {
    if (threadIdx.x < s) red[threadIdx.x] += red[threadIdx.x + s];
    __syncthreads();
  }
  if (threadIdx.x == 0) atomicAdd(&st->kldSum, (double)red[0]);
}

// ---------------- exact top-512 radix select over triu(radj) ----------------
// Row-based: block = row, threads scan cols row+1..N-1 only.
__global__ __launch_bounds__(256)
void radix_count_val(const float* __restrict__ radj, SelState* st,
                     int shift, unsigned mask)
{
  __shared__ unsigned h[256];
  h[threadIdx.x] = 0; __syncthreads();
  const int row = blockIdx.x;
  const unsigned pref = st->prefix & mask;
  for (int c = row + 1 + threadIdx.x; c < NN; c += 256) {
    unsigned b = __float_as_uint(radj[(long long)row * NN + c]);
    if ((b & mask) == pref) atomicAdd(&h[(b >> shift) & 255], 1u);
  }
  __syncthreads();
  if (h[threadIdx.x]) atomicAdd(&st->hist[threadIdx.x], h[threadIdx.x]);
}

__global__ void scan_val(SelState* st, int shift, int pass, unsigned k)
{
  unsigned rem = (pass == 0) ? k : st->remaining;
  unsigned cg = 0;
  for (int b = 255; b >= 0; --b) {
    unsigned c = st->hist[b];
    if (cg + c >= rem) { st->prefix |= ((unsigned)b) << shift; st->remaining = rem - cg; break; }
    cg += c;
  }
  for (int b = 0; b < 256; ++b) st->hist[b] = 0;
  if (pass == 3) { st->T = st->prefix; st->r = st->remaining; }
}

__global__ __launch_bounds__(256)
void radix_count_idx(const float* __restrict__ radj, SelState* st,
                     int shift, unsigned mask)
{
  __shared__ unsigned h[256];
  h[threadIdx.x] = 0; __syncthreads();
  const int row = blockIdx.x;
  const unsigned T = st->T;
  const unsigned pref = st->iprefix & mask;
  for (int c = row + 1 + threadIdx.x; c < NN; c += 256) {
    int idx = row * NN + c;
    unsigned b = __float_as_uint(radj[idx]);
    if (b != T) continue;
    unsigned u = (unsigned)idx;
    if ((u & mask) == pref) atomicAdd(&h[(u >> shift) & 255], 1u);
  }
  __syncthreads();
  if (h[threadIdx.x]) atomicAdd(&st->hist[threadIdx.x], h[threadIdx.x]);
}

__global__ void scan_idx(SelState* st, int shift, int pass)
{
  unsigned rem = (pass == 0) ? st->r : st->iremaining;
  unsigned cl = 0;
  for (int b = 0; b < 256; ++b) {
    unsigned c = st->hist[b];
    if (cl + c >= rem) { st->iprefix |= ((unsigned)b) << shift; st->iremaining = rem - cl; break; }
    cl += c;
  }
  for (int b = 0; b < 256; ++b) st->hist[b] = 0;
  if (pass == 3) st->Ithr = st->iprefix;
}

__global__ __launch_bounds__(256)
void collect_kernel(const float* __restrict__ radj, SelState* st,
                    unsigned* __restrict__ cand_bits, unsigned* __restrict__ cand_idx)
{
  const int row = blockIdx.x;
  const unsigned T = st->T, It = st->Ithr;
  for (int c = row + 1 + threadIdx.x; c < NN; c += 256) {
    int idx = row * NN + c;
    unsigned b = __float_as_uint(radj[idx]);
    if (b > T || (b == T && (unsigned)idx <= It)) {
      unsigned p = atomicAdd(&st->cTotal, 1u);
      if (p < (unsigned)TOPK) { cand_bits[p] = b; cand_idx[p] = (unsigned)idx; }
    }
  }
}

__global__ __launch_bounds__(512)
void rank_sort(const unsigned* __restrict__ cand_bits,
               const unsigned* __restrict__ cand_idx, unsigned* __restrict__ ord)
{
  __shared__ unsigned vb[512], vi[512];
  int t = threadIdx.x;
  vb[t] = cand_bits[t]; vi[t] = cand_idx[t];
  __syncthreads();
  unsigned b = vb[t], id = vi[t];
  int rank = 0;
  for (int u = 0; u < 512; ++u)
    rank += (vb[u] > b) || (vb[u] == b && vi[u] < id);
  ord[rank] = id;
}

__global__ __launch_bounds__(256)
void gather_rel(const unsigned* __restrict__ ord, const float* __restrict__ ns2,
                float* __restrict__ out)
{
  int r = blockIdx.x, c = threadIdx.x;
  unsigned id = ord[r];
  int a = id >> 11, b = id & 2047;
  out[r * 256 + c] = ns2[a * 256 + c] + ns2[b * 256 + c];
}

__global__ __launch_bounds__(512)
void finalize_kernel(const SelState* st, float* __restrict__ out)
{
  int t = threadIdx.x;
  out[TOPK * H2D + t] = 0.0f;                 // rel_mask: all False
  if (t == 0) {
    double s   = st->labSum;
    double nn  = (double)NN * NN;
    double pw  = (nn - s + NN) / (s - NN + 0.01);
    double nrm = nn / (nn - s + NN);
    out[TOPK * H2D + TOPK + 0] = (float)(nrm * (pw * st->sum1 + st->sum0) / nn);
    out[TOPK * H2D + TOPK + 1] = (float)(0.5 * st->kldSum / nn);
  }
}

} // namespace

extern "C" void kernel_launch(void* const* d_in, const int* in_sizes, int n_in,
                              void* d_out, int out_size, void* d_ws, size_t ws_size,
                              hipStream_t stream)
{
  (void)in_sizes; (void)n_in; (void)out_size; (void)ws_size;
  const float* ns_emb    = (const float*)d_in[0];
  const float* adj       = (const float*)d_in[1];
  const float* adj_prior = (const float*)d_in[2];
  const float* cond      = (const float*)d_in[3];
  const float* labels    = (const float*)d_in[4];
  const float* eps       = (const float*)d_in[5];
  const float* W_map     = (const float*)d_in[6];
  const float* Wb[2][7];
  for (int k = 0; k < 14; ++k) Wb[k / 7][k % 7] = (const float*)d_in[7 + k];
  float* out = (float*)d_out;

  // ---- workspace carve ----
  char* w = (char*)d_ws;
  SelState* st = (SelState*)w;               w += 2048;
  unsigned* cand_bits = (unsigned*)w;        w += TOPK * 4;
  unsigned* cand_idx  = (unsigned*)w;        w += TOPK * 4;
  unsigned* ord       = (unsigned*)w;        w += TOPK * 4;
  w = (char*)(((uintptr_t)w + 255) & ~(uintptr_t)255);
  int*   ellCnt[2]; int* ellCol[2]; float* ellVal[2];
  for (int b = 0; b < 2; ++b) {
    ellCnt[b] = (int*)w;   w += NN * 4;
    ellCol[b] = (int*)w;   w += (size_t)NN * CAP * 4;
    ellVal[b] = (float*)w; w += (size_t)NN * CAP * 4;
  }
  float* bufS  = (float*)w;  w += (size_t)NN * H1D * 4;
  float* bufH  = (float*)w;  w += (size_t)NN * H1D * 4;
  float* bufQ  = (float*)w;  w += (size_t)NN * H1D * 4;
  float* bufO  = (float*)w;  w += (size_t)NN * H1D * 4;
  float* bufSC = (float*)w;  w += (size_t)2 * NN * 256 * 4;
  float* bufK  = (float*)w;  w += (size_t)LCD * H1D * 4;
  float* bufV  = (float*)w;  w += (size_t)LCD * H1D * 4;
  float* bufT2 = (float*)w;  w += (size_t)NN * H1D * 4;
  float* mulv[2];
  mulv[0] = (float*)w;       w += (size_t)NN * H1D * 4;
  mulv[1] = (float*)w;       w += (size_t)NN * H1D * 4;
  float* zb   = (float*)w;   w += (size_t)NN * H2D * 4;
  float* ns2  = (float*)w;   w += (size_t)NN * H2D * 4;
  float* radj = (float*)w;   w += (size_t)NN * NN * 4;

  hipMemsetAsync(st, 0, sizeof(SelState), stream);

  // ---- sparse adjacency build ----
  build_ell<<<dim3(NN), dim3(64), 0, stream>>>(adj,       ellCnt[0], ellCol[0], ellVal[0]);
  build_ell<<<dim3(NN), dim3(64), 0, stream>>>(adj_prior, ellCnt[1], ellCol[1], ellVal[1]);

  // ---- two encoder branches ----
  for (int br = 0; br < 2; ++br) {
    const float *W_hid = Wb[br][0], *Wq = Wb[br][1], *Wk = Wb[br][2],
                *Wv = Wb[br][3], *Wo = Wb[br][4], *W_mu = Wb[br][5], *W_var = Wb[br][6];

    // gcn1: S = leaky(ns_emb @ W_hid); H = leaky(adj @ S)   (sparse)
    gemm64<1,0,0><<<dim3(8,32,1), 256, 0, stream>>>(ns_emb, W_hid, bufS,
        NN, H1D, FIN, FIN, H1D, H1D, 1.f, 0, 0, 0);
    spmm_leaky<<<dim3(NN), 256, 0, stream>>>(ellCnt[br], ellCol[br], ellVal[br], bufS, bufH);

    // mha projections
    gemm64<0,0,0><<<dim3(8,32,1), 256, 0, stream>>>(bufH, Wq, bufQ,
        NN, H1D, H1D, H1D, H1D, H1D, 1.f, 0, 0, 0);
    gemm64<0,0,0><<<dim3(8,4,1),  256, 0, stream>>>(cond, Wk, bufK,
        LCD, H1D, FIN, FIN, H1D, H1D, 1.f, 0, 0, 0);
    gemm64<0,0,0><<<dim3(8,4,1),  256, 0, stream>>>(cond, Wv, bufV,
        LCD, H1D, FIN, FIN, H1D, H1D, 1.f, 0, 0, 0);

    // scores (2 heads), softmax, attn @ V
    gemm64<0,1,0><<<dim3(4,32,2), 256, 0, stream>>>(bufQ, bufK, bufSC,
        NN, LCD, 256, H1D, H1D, 256, 0.0625f, 256, 256, (long long)NN * 256);
    softmax256<<<dim3(2 * NN), 256, 0, stream>>>(bufSC);
    gemm64<0,0,0><<<dim3(4,32,2), 256, 0, stream>>>(bufSC, bufV, bufO,
        NN, 256, LCD, 256, H1D, H1D, 1.f, (long long)NN * 256, 256, 256);

    // o @ Wo
    gemm64<0,0,0><<<dim3(8,32,1), 256, 0, stream>>>(bufO, Wo, bufH,
        NN, H1D, H1D, H1D, H1D, H1D, 1.f, 0, 0, 0);

    // mu/var packed: T2 = leaky(H @ [W_mu | W_var]); mulv = leaky(adj @ T2) (sparse)
    gemm64<1,0,0><<<dim3(4,32,1), 256, 0, stream>>>(bufH, W_mu, bufT2,
        NN, H2D, H1D, H1D, H2D, H1D, 1.f, 0, 0, 0);
    gemm64<1,0,0><<<dim3(4,32,1), 256, 0, stream>>>(bufH, W_var, bufT2 + H2D,
        NN, H2D, H1D, H1D, H2D, H1D, 1.f, 0, 0, 0);
    spmm_leaky<<<dim3(NN), 256, 0, stream>>>(ellCnt[br], ellCol[br], ellVal[br], bufT2, mulv[br]);
  }

  // ---- decoder + losses ----
  z_kernel<<<dim3(NN), 256, 0, stream>>>(eps, mulv[0], zb);
  gemm64<2,1,1><<<dim3(32,32,1), 256, 0, stream>>>(zb, zb, radj,
      NN, NN, H2D, H2D, H2D, NN, 1.f, 0, 0, 0);      // sigmoid(z @ z^T), symmetric
  gemm64<1,0,0><<<dim3(4,32,1), 256, 0, stream>>>(ns_emb, W_map, ns2,
      NN, H2D, FIN, FIN, H2D, H2D, 1.f, 0, 0, 0);

  bce_kernel<<<dim3(512), 256, 0, stream>>>(radj, labels, st);
  kld_kernel<<<dim3(256), 256, 0, stream>>>(mulv[0], mulv[1], st);

  // ---- exact top-512 of triu(radj) ----
  const unsigned masks[4] = {0u, 0xFF000000u, 0xFFFF0000u, 0xFFFFFF00u};
  for (int pass = 0; pass < 4; ++pass) {
    int shift = 24 - 8 * pass;
    radix_count_val<<<dim3(NN), 256, 0, stream>>>(radj, st, shift, masks[pass]);
    scan_val<<<dim3(1), dim3(1), 0, stream>>>(st, shift, pass, TOPK);
  }
  for (int pass = 0; pass < 4; ++pass) {
    int shift = 24 - 8 * pass;
    radix_count_idx<<<dim3(NN), 256, 0, stream>>>(radj, st, shift, masks[pass]);
    scan_idx<<<dim3(1), dim3(1), 0, stream>>>(st, shift, pass);
  }
  collect_kernel<<<dim3(NN), 256, 0, stream>>>(radj, st, cand_bits, cand_idx);
  rank_sort<<<dim3(1), dim3(512), 0, stream>>>(cand_bits, cand_idx, ord);
  gather_rel<<<dim3(TOPK), 256, 0, stream>>>(ord, ns2, out);
  finalize_kernel<<<dim3(1), dim3(512), 0, stream>>>(st, out);
}

// Round 3
// 698.377 us; speedup vs baseline: 4.7415x; 1.7890x over previous
//
#include <hip/hip_runtime.h>
#include <math.h>
#include <stdint.h>

// GCNModelVAE forward on MI355X — round 2.
// Diagnosis from round 1 counters: gemm64 at 10% occupancy (256 blocks = 1 block/CU),
// VALUBusy 19.5% -> latency-bound. Fixes:
//  - batch post+prior branches (and heads / Wk|Wv / Wmu|Wvar) into single launches
//    via pointer table indexed by blockIdx.z (grid 512 blocks = 2 blocks/CU)
//  - double-buffered LDS + register prefetch, one barrier per K-step
//  - parallel scan kernels; index tie-break via row-cut instead of 4 radix passes
//  - aliasing workspace arena (~41 MB)

namespace {

constexpr int NN   = 2048;
constexpr int FIN  = 768;
constexpr int H1D  = 512;
constexpr int H2D  = 256;
constexpr int LCD  = 256;
constexpr int TOPK = 512;
constexpr int TOTE = NN * NN;
constexpr int CAP  = 96;

struct SelState {
  unsigned hist[256];
  unsigned prefix, remaining, T, r;
  unsigned tieRow, tieRem, Ithr;
  unsigned cTotal;
  double sum1, sum0, labSum, kldSum;
};

struct B8 { const float* A[8]; const float* B[8]; float* C[8]; };
struct EB { const float* adj[2]; int* cnt[2]; int* col[2]; float* val[2]; };
struct SB { const int* cnt[2]; const int* col[2]; const float* val[2];
            const float* S[2]; float* out[2]; };

__device__ __forceinline__ float logsig(float x) {
  if (x >= 0.f) return -log1pf(expf(-x));
  return x - log1pf(expf(x));
}
__device__ __forceinline__ float leaky(float v) { return v >= 0.f ? v : 0.01f * v; }

// ---------------- dense fp32 GEMM: 64x64 tile, 4x4 micro, double-buffered ----------------
// M%64==0 (or M=256), N%64==0, K%16==0. TRANSB=0: B[k*ldb+n]; 1: B[n*ldb+k].
// ACT: 0 none, 1 leaky, 2 sigmoid. SYMU: A@A^T upper blocks + mirrored store.
template<int ACT, int TRANSB, int SYMU>
__global__ __launch_bounds__(256)
void gemm64(B8 bat, int M, int N, int K, int lda, int ldb, int ldc, float scale)
{
  if (SYMU && (int)blockIdx.x < (int)blockIdx.y) return;
  const float* __restrict__ A  = bat.A[blockIdx.z];
  const float* __restrict__ Bp = bat.B[blockIdx.z];
  float* __restrict__ C        = bat.C[blockIdx.z];
  __shared__ float As[2][16][68];
  __shared__ float Bs[2][16][68];
  const int t  = threadIdx.x;
  const int bm = blockIdx.y * 64, bn = blockIdx.x * 64;
  const int lr = t >> 2, lq = t & 3;        // 64 rows x 4 k-quads staging
  const int bkr = t >> 4, bnq = t & 15;     // 16 k x 16 n-quads (B no-trans)
  const int tx = t & 15, ty = t >> 4;
  const float* Aptr = A  + (long long)(bm + lr) * lda + lq * 4;
  const float* Bt   = Bp + (long long)(bn + lr) * ldb + lq * 4;
  const float* Bn   = Bp + (long long)bkr * ldb + bn + bnq * 4;
  float acc[4][4] = {};

  float4 av = *(const float4*)Aptr;
  float4 bv = TRANSB ? *(const float4*)Bt : *(const float4*)Bn;
  As[0][lq*4+0][lr]=av.x; As[0][lq*4+1][lr]=av.y; As[0][lq*4+2][lr]=av.z; As[0][lq*4+3][lr]=av.w;
  if (TRANSB) {
    Bs[0][lq*4+0][lr]=bv.x; Bs[0][lq*4+1][lr]=bv.y; Bs[0][lq*4+2][lr]=bv.z; Bs[0][lq*4+3][lr]=bv.w;
  } else {
    *(float4*)&Bs[0][bkr][bnq*4] = bv;
  }
  __syncthreads();
  int cur = 0;
  for (int k0 = 16; k0 < K; k0 += 16) {
    av = *(const float4*)(Aptr + k0);
    bv = TRANSB ? *(const float4*)(Bt + k0) : *(const float4*)(Bn + (long long)k0 * ldb);
    #pragma unroll
    for (int kk = 0; kk < 16; ++kk) {
      float4 a = *(const float4*)&As[cur][kk][ty*4];
      float4 b = *(const float4*)&Bs[cur][kk][tx*4];
      acc[0][0]+=a.x*b.x; acc[0][1]+=a.x*b.y; acc[0][2]+=a.x*b.z; acc[0][3]+=a.x*b.w;
      acc[1][0]+=a.y*b.x; acc[1][1]+=a.y*b.y; acc[1][2]+=a.y*b.z; acc[1][3]+=a.y*b.w;
      acc[2][0]+=a.z*b.x; acc[2][1]+=a.z*b.y; acc[2][2]+=a.z*b.z; acc[2][3]+=a.z*b.w;
      acc[3][0]+=a.w*b.x; acc[3][1]+=a.w*b.y; acc[3][2]+=a.w*b.z; acc[3][3]+=a.w*b.w;
    }
    const int nb = cur ^ 1;
    As[nb][lq*4+0][lr]=av.x; As[nb][lq*4+1][lr]=av.y; As[nb][lq*4+2][lr]=av.z; As[nb][lq*4+3][lr]=av.w;
    if (TRANSB) {
      Bs[nb][lq*4+0][lr]=bv.x; Bs[nb][lq*4+1][lr]=bv.y; Bs[nb][lq*4+2][lr]=bv.z; Bs[nb][lq*4+3][lr]=bv.w;
    } else {
      *(float4*)&Bs[nb][bkr][bnq*4] = bv;
    }
    __syncthreads();
    cur = nb;
  }
  #pragma unroll
  for (int kk = 0; kk < 16; ++kk) {
    float4 a = *(const float4*)&As[cur][kk][ty*4];
    float4 b = *(const float4*)&Bs[cur][kk][tx*4];
    acc[0][0]+=a.x*b.x; acc[0][1]+=a.x*b.y; acc[0][2]+=a.x*b.z; acc[0][3]+=a.x*b.w;
    acc[1][0]+=a.y*b.x; acc[1][1]+=a.y*b.y; acc[1][2]+=a.y*b.z; acc[1][3]+=a.y*b.w;
    acc[2][0]+=a.z*b.x; acc[2][1]+=a.z*b.y; acc[2][2]+=a.z*b.z; acc[2][3]+=a.z*b.w;
    acc[3][0]+=a.w*b.x; acc[3][1]+=a.w*b.y; acc[3][2]+=a.w*b.z; acc[3][3]+=a.w*b.w;
  }
  float o[4][4];
  #pragma unroll
  for (int i = 0; i < 4; ++i)
    #pragma unroll
    for (int j = 0; j < 4; ++j) {
      float v = acc[i][j] * scale;
      if (ACT == 1)      v = leaky(v);
      else if (ACT == 2) v = 1.f / (1.f + expf(-v));
      o[i][j] = v;
    }
  #pragma unroll
  for (int i = 0; i < 4; ++i)
    *(float4*)&C[(long long)(bm + ty*4 + i) * ldc + bn + tx*4] =
        make_float4(o[i][0], o[i][1], o[i][2], o[i][3]);
  if (SYMU) {
    #pragma unroll
    for (int j = 0; j < 4; ++j)
      *(float4*)&C[(long long)(bn + tx*4 + j) * ldc + bm + ty*4] =
          make_float4(o[0][j], o[1][j], o[2][j], o[3][j]);
  }
}

// ---------------- ELL build (batched over 2 adjacencies) ----------------
__global__ __launch_bounds__(64)
void build_ell(EB eb)
{
  const int b = blockIdx.y, row = blockIdx.x, lane = threadIdx.x;
  const float* adj = eb.adj[b];
  int base = 0;
  for (int c0 = 0; c0 < NN; c0 += 64) {
    float v = adj[(long long)row * NN + c0 + lane];
    unsigned long long m = __ballot(v != 0.0f);
    if (v != 0.0f) {
      int pos = base + __popcll(m & ((1ull << lane) - 1ull));
      if (pos < CAP) { eb.col[b][row * CAP + pos] = c0 + lane; eb.val[b][row * CAP + pos] = v; }
    }
    base += __popcll(m);
  }
  if (lane == 0) eb.cnt[b][row] = base > CAP ? CAP : base;
}

// ---------------- batched spMM: out[row] = leaky(sum val_i * S[col_i]) over 512 cols ----------------
__global__ __launch_bounds__(256)
void spmm_leaky(SB sb)
{
  const int b = blockIdx.y, row = blockIdx.x, t = threadIdx.x;
  __shared__ int   sc[CAP];
  __shared__ float sv[CAP];
  __shared__ int   n;
  if (t == 0) n = sb.cnt[b][row];
  if (t < CAP) { sc[t] = sb.col[b][row * CAP + t]; sv[t] = sb.val[b][row * CAP + t]; }
  __syncthreads();
  const int m = n;
  const float* S = sb.S[b];
  float a0 = 0.f, a1 = 0.f;
  for (int i = 0; i < m; ++i) {
    const float* Sr = S + (long long)sc[i] * 512;
    float v = sv[i];
    a0 += v * Sr[t];
    a1 += v * Sr[t + 256];
  }
  sb.out[b][(long long)row * 512 + t]       = leaky(a0);
  sb.out[b][(long long)row * 512 + t + 256] = leaky(a1);
}

// ---------------- softmax over rows of length 256 ----------------
__global__ __launch_bounds__(256)
void softmax256(float* __restrict__ x)
{
  __shared__ float red[256];
  const int row = blockIdx.x, t = threadIdx.x;
  float v = x[(long long)row * 256 + t];
  red[t] = v; __syncthreads();
  for (int s = 128; s > 0; s >>= 1) { if (t < s) red[t] = fmaxf(red[t], red[t + s]); __syncthreads(); }
  float m = red[0]; __syncthreads();
  float e = expf(v - m);
  red[t] = e; __syncthreads();
  for (int s = 128; s > 0; s >>= 1) { if (t < s) red[t] += red[t + s]; __syncthreads(); }
  x[(long long)row * 256 + t] = e / red[0];
}

// ---------------- z = eps * exp(0.5*lv) + mu ----------------
__global__ __launch_bounds__(256)
void z_kernel(const float* __restrict__ eps, const float* __restrict__ mulv,
              float* __restrict__ z)
{
  int idx = blockIdx.x * 256 + threadIdx.x;
  int r = idx >> 8, c = idx & 255;
  z[idx] = eps[idx] * expf(0.5f * mulv[r * 512 + 256 + c]) + mulv[r * 512 + c];
}

// ---------------- BCE partials ----------------
__global__ __launch_bounds__(256)
void bce_kernel(const float* __restrict__ radj, const float* __restrict__ labels,
                SelState* st)
{
  float s1 = 0.f, s0 = 0.f, sl = 0.f;
  for (int idx = blockIdx.x * 256 + threadIdx.x; idx < TOTE; idx += 512 * 256) {
    float p = radj[idx], lb = labels[idx];
    s1 += lb * (-logsig(p));
    s0 += (1.f - lb) * (-logsig(-p));
    sl += lb;
  }
  __shared__ float r1[256], r0[256], rl[256];
  r1[threadIdx.x] = s1; r0[threadIdx.x] = s0; rl[threadIdx.x] = sl;
  __syncthreads();
  for (int s = 128; s > 0; s >>= 1) {
    if (threadIdx.x < s) {
      r1[threadIdx.x] += r1[threadIdx.x + s];
      r0[threadIdx.x] += r0[threadIdx.x + s];
      rl[threadIdx.x] += rl[threadIdx.x + s];
    }
    __syncthreads();
  }
  if (threadIdx.x == 0) {
    atomicAdd(&st->sum1,   (double)r1[0]);
    atomicAdd(&st->sum0,   (double)r0[0]);
    atomicAdd(&st->labSum, (double)rl[0]);
  }
}

// ---------------- KLD partials ----------------
__global__ __launch_bounds__(256)
void kld_kernel(const float* __restrict__ mpo, const float* __restrict__ mpr,
                SelState* st)
{
  float acc = 0.f;
  for (int idx = blockIdx.x * 256 + threadIdx.x; idx < NN * H2D; idx += 256 * 256) {
    int r = idx >> 8, c = idx & 255;
    float mu_po = mpo[r * 512 + c], lv_po = mpo[r * 512 + 256 + c];
    float mu_pr = mpr[r * 512 + c], lv_pr = mpr[r * 512 + 256 + c];
    float d = mu_pr - mu_po, dl = lv_po - lv_pr;
    acc += d * d * expf(-lv_pr) + expf(dl) - 1.f - dl;
  }
  __shared__ float red[256];
  red[threadIdx.x] = acc; __syncthreads();
  for (int s = 128; s > 0; s >>= 1) {
    if (threadIdx.x < s) red[threadIdx.x] += red[threadIdx.x + s];
    __syncthreads();
  }
  if (threadIdx.x == 0) atomicAdd(&st->kldSum, (double)red[0]);
}

// ---------------- top-512 value radix select over triu(radj) ----------------
__global__ __launch_bounds__(256)
void radix_count_val(const float* __restrict__ radj, SelState* st,
                     int shift, unsigned mask)
{
  __shared__ unsigned h[256];
  h[threadIdx.x] = 0; __syncthreads();
  const int row = blockIdx.x;
  const unsigned pref = st->prefix & mask;
  for (int c = row + 1 + threadIdx.x; c < NN; c += 256) {
    unsigned b = __float_as_uint(radj[(long long)row * NN + c]);
    if ((b & mask) == pref) atomicAdd(&h[(b >> shift) & 255], 1u);
  }
  __syncthreads();
  if (h[threadIdx.x]) atomicAdd(&st->hist[threadIdx.x], h[threadIdx.x]);
}

__global__ __launch_bounds__(256)
void scan_val(SelState* st, int shift, int pass, unsigned k)
{
  __shared__ unsigned h[256];
  const int b = threadIdx.x;
  const unsigned rem = (pass == 0) ? k : st->remaining;
  const unsigned hv = st->hist[b];
  h[b] = hv; __syncthreads();
  unsigned s = 0;
  for (int j = b; j < 256; ++j) s += h[j];   // suffix sum (desc order = larger values first)
  const unsigned cgt = s - hv;               // count strictly greater bucket
  if (cgt < rem && rem <= s) {
    st->prefix |= ((unsigned)b) << shift;
    st->remaining = rem - cgt;
    if (pass == 3) { st->T = st->prefix; st->r = st->remaining; }
  }
  st->hist[b] = 0;
}

// ---------------- index tie-break: per-row tie counts -> cut row -> exact column ----------------
__global__ __launch_bounds__(256)
void tie_rows(const float* __restrict__ radj, const SelState* st,
              unsigned* __restrict__ rowTies)
{
  __shared__ unsigned red[256];
  const int row = blockIdx.x, t = threadIdx.x;
  const unsigned T = st->T;
  unsigned c0 = 0;
  for (int c = row + 1 + t; c < NN; c += 256)
    c0 += (__float_as_uint(radj[(long long)row * NN + c]) == T);
  red[t] = c0; __syncthreads();
  for (int s = 128; s > 0; s >>= 1) { if (t < s) red[t] += red[t + s]; __syncthreads(); }
  if (t == 0) rowTies[row] = red[0];
}

__global__ __launch_bounds__(256)
void cut_row(const unsigned* __restrict__ rowTies, SelState* st)
{
  __shared__ unsigned ps[256];
  const int t = threadIdx.x;
  unsigned loc[8], s = 0;
  for (int i = 0; i < 8; ++i) { loc[i] = rowTies[t * 8 + i]; s += loc[i]; }
  ps[t] = s; __syncthreads();
  for (int sh = 1; sh < 256; sh <<= 1) {
    unsigned v = (t >= sh) ? ps[t - sh] : 0; __syncthreads();
    ps[t] += v; __syncthreads();
  }
  const unsigned r = st->r;
  const unsigned exc = ps[t] - s;
  if (r > exc && r <= ps[t]) {
    unsigned cum = exc;
    for (int i = 0; i < 8; ++i) {
      if (r <= cum + loc[i]) { st->tieRow = t * 8 + i; st->tieRem = r - cum; break; }
      cum += loc[i];
    }
  }
}

__global__ __launch_bounds__(256)
void find_col(const float* __restrict__ radj, SelState* st)
{
  __shared__ unsigned ps[256];
  __shared__ unsigned sbase, sdone;
  const int t = threadIdx.x;
  if (t == 0) { sbase = 0; sdone = 0; }
  __syncthreads();
  const int      R   = (int)st->tieRow;
  const unsigned rem = st->tieRem, T = st->T;
  for (int c0 = R + 1; c0 < NN; c0 += 256) {
    if (sdone) break;
    const int c = c0 + t;
    unsigned f = (c < NN && __float_as_uint(radj[(long long)R * NN + c]) == T) ? 1u : 0u;
    ps[t] = f; __syncthreads();
    for (int sh = 1; sh < 256; sh <<= 1) {
      unsigned v = (t >= sh) ? ps[t - sh] : 0; __syncthreads();
      ps[t] += v; __syncthreads();
    }
    if (f && sbase + ps[t] == rem) { st->Ithr = (unsigned)(R * NN + c); sdone = 1; }
    const unsigned tot = ps[255];
    __syncthreads();
    if (t == 0) sbase += tot;
    __syncthreads();
  }
}

__global__ __launch_bounds__(256)
void collect_kernel(const float* __restrict__ radj, SelState* st,
                    unsigned* __restrict__ cand_bits, unsigned* __restrict__ cand_idx)
{
  const int row = blockIdx.x;
  const unsigned T = st->T, It = st->Ithr;
  for (int c = row + 1 + threadIdx.x; c < NN; c += 256) {
    int idx = row * NN + c;
    unsigned b = __float_as_uint(radj[idx]);
    if (b > T || (b == T && (unsigned)idx <= It)) {
      unsigned p = atomicAdd(&st->cTotal, 1u);
      if (p < (unsigned)TOPK) { cand_bits[p] = b; cand_idx[p] = (unsigned)idx; }
    }
  }
}

__global__ __launch_bounds__(512)
void rank_sort(const unsigned* __restrict__ cand_bits,
               const unsigned* __restrict__ cand_idx, unsigned* __restrict__ ord)
{
  __shared__ unsigned vb[512], vi[512];
  const int t = threadIdx.x;
  vb[t] = cand_bits[t]; vi[t] = cand_idx[t];
  __syncthreads();
  unsigned b = vb[t], id = vi[t];
  int rank = 0;
  for (int u = 0; u < 512; ++u)
    rank += (vb[u] > b) || (vb[u] == b && vi[u] < id);
  ord[rank] = id;
}

__global__ __launch_bounds__(256)
void gather_rel(const unsigned* __restrict__ ord, const float* __restrict__ ns2,
                float* __restrict__ out)
{
  const int r = blockIdx.x, c = threadIdx.x;
  unsigned id = ord[r];
  int a = id >> 11, b = id & 2047;
  out[r * 256 + c] = ns2[a * 256 + c] + ns2[b * 256 + c];
}

__global__ __launch_bounds__(512)
void finalize_kernel(const SelState* st, float* __restrict__ out)
{
  const int t = threadIdx.x;
  out[TOPK * H2D + t] = 0.0f;                 // rel_mask: all False
  if (t == 0) {
    double s   = st->labSum;
    double nn  = (double)NN * NN;
    double pw  = (nn - s + NN) / (s - NN + 0.01);
    double nrm = nn / (nn - s + NN);
    out[TOPK * H2D + TOPK + 0] = (float)(nrm * (pw * st->sum1 + st->sum0) / nn);
    out[TOPK * H2D + TOPK + 1] = (float)(0.5 * st->kldSum / nn);
  }
}

} // namespace

extern "C" void kernel_launch(void* const* d_in, const int* in_sizes, int n_in,
                              void* d_out, int out_size, void* d_ws, size_t ws_size,
                              hipStream_t stream)
{
  (void)in_sizes; (void)n_in; (void)out_size; (void)ws_size;
  const float* ns_emb    = (const float*)d_in[0];
  const float* adj       = (const float*)d_in[1];
  const float* adj_prior = (const float*)d_in[2];
  const float* cond      = (const float*)d_in[3];
  const float* labels    = (const float*)d_in[4];
  const float* eps       = (const float*)d_in[5];
  const float* W_map     = (const float*)d_in[6];
  const float* Wb[2][7];
  for (int k = 0; k < 14; ++k) Wb[k / 7][k % 7] = (const float*)d_in[7 + k];
  float* out = (float*)d_out;

  // ---- workspace (aliasing arena, ~41 MB) ----
  char* w = (char*)d_ws;
  SelState* st = (SelState*)w;               w += 2048;
  unsigned* cand_bits = (unsigned*)w;        w += TOPK * 4;
  unsigned* cand_idx  = (unsigned*)w;        w += TOPK * 4;
  unsigned* ord       = (unsigned*)w;        w += TOPK * 4;
  unsigned* rowTies   = (unsigned*)w;        w += NN * 4;
  w = (char*)(((uintptr_t)w + 255) & ~(uintptr_t)255);
  int* ellCnt[2]; int* ellCol[2]; float* ellVal[2];
  for (int b = 0; b < 2; ++b) {
    ellCnt[b] = (int*)w;   w += NN * 4;
    ellCol[b] = (int*)w;   w += (size_t)NN * CAP * 4;
    ellVal[b] = (float*)w; w += (size_t)NN * CAP * 4;
  }
  const long long NNH1 = (long long)NN * H1D;   // 1,048,576 floats
  const long long LCH  = (long long)LCD * H1D;  //   131,072 floats
  float* AR = (float*)w;  w += (size_t)(4 * NNH1 + 4 * LCH + 2 * NNH1) * 4;  // 26 MB arena
  float* mulv[2];
  mulv[0] = (float*)w;    w += (size_t)NNH1 * 4;
  mulv[1] = (float*)w;    w += (size_t)NNH1 * 4;
  float* zb  = (float*)w; w += (size_t)NN * H2D * 4;
  float* ns2 = (float*)w; w += (size_t)NN * H2D * 4;

  // arena aliases (lifetimes verified: S->H->Q->K/V->SC->O->H2->T2->radj)
  float* S[2]  = { AR,            AR + NNH1 };
  float* Q[2]  = { AR,            AR + NNH1 };            // over S (S dead after spmm1)
  float* H[2]  = { AR + 2*NNH1,   AR + 3*NNH1 };
  float* O[2]  = { AR + 2*NNH1,   AR + 3*NNH1 };          // over H (H dead after Q-proj)
  float* Kb[2] = { AR + 4*NNH1,             AR + 4*NNH1 + LCH };
  float* Vb[2] = { AR + 4*NNH1 + 2*LCH,     AR + 4*NNH1 + 3*LCH };
  float* SC    =   AR + 4*NNH1 + 4*LCH;                   // 4 x [2048,256]
  float* T2[2] = { SC,            SC + NNH1 };            // over SC (SC dead after attnV)
  float* H2[2] = { AR,            AR + NNH1 };            // over Q (Q dead after scores)
  float* radj  =   AR;                                    // decoder phase: all arena dead

  hipMemsetAsync(st, 0, sizeof(SelState), stream);

  // ---- ELL build (both adjacencies) ----
  {
    EB eb{};
    eb.adj[0]=adj; eb.adj[1]=adj_prior;
    for (int b=0;b<2;++b){ eb.cnt[b]=ellCnt[b]; eb.col[b]=ellCol[b]; eb.val[b]=ellVal[b]; }
    build_ell<<<dim3(NN,2), 64, 0, stream>>>(eb);
  }

  // ---- encoder (post+prior batched) ----
  { // S[br] = leaky(ns_emb @ W_hid[br])
    B8 b{};
    for (int br=0;br<2;++br){ b.A[br]=ns_emb; b.B[br]=Wb[br][0]; b.C[br]=S[br]; }
    gemm64<1,0,0><<<dim3(8,32,2), 256, 0, stream>>>(b, NN, H1D, FIN, FIN, H1D, H1D, 1.f);
  }
  { // H[br] = leaky(adj[br] @ S[br])
    SB sb{};
    for (int br=0;br<2;++br){ sb.cnt[br]=ellCnt[br]; sb.col[br]=ellCol[br];
      sb.val[br]=ellVal[br]; sb.S[br]=S[br]; sb.out[br]=H[br]; }
    spmm_leaky<<<dim3(NN,2), 256, 0, stream>>>(sb);
  }
  { // Q[br] = H[br] @ Wq[br]
    B8 b{};
    for (int br=0;br<2;++br){ b.A[br]=H[br]; b.B[br]=Wb[br][1]; b.C[br]=Q[br]; }
    gemm64<0,0,0><<<dim3(8,32,2), 256, 0, stream>>>(b, NN, H1D, H1D, H1D, H1D, H1D, 1.f);
  }
  { // K/V[br] = cond @ Wk/Wv[br]   (4-way batch)
    B8 b{};
    for (int br=0;br<2;++br){
      b.A[br]=cond;   b.B[br]=Wb[br][2];   b.C[br]=Kb[br];
      b.A[2+br]=cond; b.B[2+br]=Wb[br][3]; b.C[2+br]=Vb[br];
    }
    gemm64<0,0,0><<<dim3(8,4,4), 256, 0, stream>>>(b, LCD, H1D, FIN, FIN, H1D, H1D, 1.f);
  }
  { // scores[br,hd] = Q_hd @ K_hd^T / 16
    B8 b{};
    for (int br=0;br<2;++br) for (int hd=0;hd<2;++hd){
      int z = br*2+hd;
      b.A[z]=Q[br]+hd*256; b.B[z]=Kb[br]+hd*256; b.C[z]=SC+(long long)z*NN*256;
    }
    gemm64<0,1,0><<<dim3(4,32,4), 256, 0, stream>>>(b, NN, LCD, 256, H1D, H1D, 256, 0.0625f);
  }
  softmax256<<<dim3(4*NN), 256, 0, stream>>>(SC);
  { // O[br,hd-part] = attn @ V_hd
    B8 b{};
    for (int br=0;br<2;++br) for (int hd=0;hd<2;++hd){
      int z = br*2+hd;
      b.A[z]=SC+(long long)z*NN*256; b.B[z]=Vb[br]+hd*256; b.C[z]=O[br]+hd*256;
    }
    gemm64<0,0,0><<<dim3(4,32,4), 256, 0, stream>>>(b, NN, 256, LCD, 256, H1D, H1D, 1.f);
  }
  { // H2[br] = O[br] @ Wo[br]
    B8 b{};
    for (int br=0;br<2;++br){ b.A[br]=O[br]; b.B[br]=Wb[br][4]; b.C[br]=H2[br]; }
    gemm64<0,0,0><<<dim3(8,32,2), 256, 0, stream>>>(b, NN, H1D, H1D, H1D, H1D, H1D, 1.f);
  }
  { // T2[br] = leaky(H2[br] @ [W_mu|W_var][br])  (4-way batch, cols 0/256)
    B8 b{};
    for (int br=0;br<2;++br){
      b.A[br]=H2[br];   b.B[br]=Wb[br][5];   b.C[br]=T2[br];
      b.A[2+br]=H2[br]; b.B[2+br]=Wb[br][6]; b.C[2+br]=T2[br]+H2D;
    }
    gemm64<1,0,0><<<dim3(4,32,4), 256, 0, stream>>>(b, NN, H2D, H1D, H1D, H2D, H1D, 1.f);
  }
  { // mulv[br] = leaky(adj[br] @ T2[br])
    SB sb{};
    for (int br=0;br<2;++br){ sb.cnt[br]=ellCnt[br]; sb.col[br]=ellCol[br];
      sb.val[br]=ellVal[br]; sb.S[br]=T2[br]; sb.out[br]=mulv[br]; }
    spmm_leaky<<<dim3(NN,2), 256, 0, stream>>>(sb);
  }

  // ---- decoder + losses ----
  z_kernel<<<dim3(NN), 256, 0, stream>>>(eps, mulv[0], zb);
  { // radj = sigmoid(z @ z^T), symmetric
    B8 b{}; b.A[0]=zb; b.B[0]=zb; b.C[0]=radj;
    gemm64<2,1,1><<<dim3(32,32,1), 256, 0, stream>>>(b, NN, NN, H2D, H2D, H2D, NN, 1.f);
  }
  { // ns2 = leaky(ns_emb @ W_map)
    B8 b{}; b.A[0]=ns_emb; b.B[0]=W_map; b.C[0]=ns2;
    gemm64<1,0,0><<<dim3(4,32,1), 256, 0, stream>>>(b, NN, H2D, FIN, FIN, H2D, H2D, 1.f);
  }
  bce_kernel<<<dim3(512), 256, 0, stream>>>(radj, labels, st);
  kld_kernel<<<dim3(256), 256, 0, stream>>>(mulv[0], mulv[1], st);

  // ---- exact top-512 of triu(radj) ----
  const unsigned masks[4] = {0u, 0xFF000000u, 0xFFFF0000u, 0xFFFFFF00u};
  for (int pass = 0; pass < 4; ++pass) {
    int shift = 24 - 8 * pass;
    radix_count_val<<<dim3(NN), 256, 0, stream>>>(radj, st, shift, masks[pass]);
    scan_val<<<dim3(1), 256, 0, stream>>>(st, shift, pass, TOPK);
  }
  tie_rows<<<dim3(NN), 256, 0, stream>>>(radj, st, rowTies);
  cut_row<<<dim3(1), 256, 0, stream>>>(rowTies, st);
  find_col<<<dim3(1), 256, 0, stream>>>(radj, st);
  collect_kernel<<<dim3(NN), 256, 0, stream>>>(radj, st, cand_bits, cand_idx);
  rank_sort<<<dim3(1), 512, 0, stream>>>(cand_bits, cand_idx, ord);
  gather_rel<<<dim3(TOPK), 256, 0, stream>>>(ord, ns2, out);
  finalize_kernel<<<dim3(1), 512, 0, stream>>>(st, out);
}

// Round 7
// 595.484 us; speedup vs baseline: 5.5608x; 1.1728x over previous
//
#include <hip/hip_runtime.h>
#include <math.h>
#include <stdint.h>

// GCNModelVAE forward on MI355X — round 3 kernel (4th submission; rounds 4-6
// lost to GPU acquisition timeouts, never executed).
// From round-2 counters: gemm64 VALUBusy 46%, occupancy 17% (2 blocks/CU), tail ~350us.
//  - KT=32 double-buffered GEMM (half the barriers), multi-slot mega launches
//  - z@zT epilogue fuses sigmoid + BCE + labSum + tie-count + per-row tie histogram
//  - top-k: fast path T=1.0f from fused count; single guarded fallback kernel
//  - wave-level softmax (no barriers), fused z+kld, ballot find_col

namespace {

constexpr int NN   = 2048;
constexpr int FIN  = 768;
constexpr int H1D  = 512;
constexpr int H2D  = 256;
constexpr int LCD  = 256;
constexpr int TOPK = 512;
constexpr int TOTE = NN * NN;
constexpr int CAP  = 96;
constexpr unsigned ONEB = 0x3F800000u;   // bits of 1.0f

struct SelState {
  unsigned cnt1, T, r, tieRow, tieRem, Ithr, cTotal, pad;
  double sum1, sum0, labSum, kldSum;
};

struct Slot  { const float* A; const float* B; float* C;
               int lda, ldb, ldc, nshift, act; float scale; };
struct Launch{ Slot s[8]; int zend[8]; };
struct EB { const float* adj[2]; int* cnt[2]; int* col[2]; float* val[2]; };
struct SB { const int* cnt[2]; const int* col[2]; const float* val[2];
            const float* S[2]; float* out[2]; };

__device__ __forceinline__ float leaky(float v) { return v >= 0.f ? v : 0.01f * v; }

// ---------------- mega GEMM: 64x64 tile, 4x4 micro, KT=32, double-buffered ----------------
// Up to 8 independent (A,B,C) slots per launch; slot found from blockIdx.x via zend[].
// All dims: M%64==0, N%64==0, K%32==0, leading dims %4==0.
template<int TRANSB>
__global__ __launch_bounds__(256)
void mega_gemm(Launch P, int K)
{
  const int bid = blockIdx.x;
  int z = 0, start = 0;
  #pragma unroll
  for (int i = 0; i < 7; ++i)
    if (bid >= P.zend[i]) { z = i + 1; start = P.zend[i]; }
  Slot sl = P.s[0];
  #pragma unroll
  for (int i = 1; i < 8; ++i) if (z == i) sl = P.s[i];
  const int local = bid - start;
  const int by = local >> sl.nshift;
  const int bx = local & ((1 << sl.nshift) - 1);

  __shared__ float As[2][32][68];
  __shared__ float Bs[2][32][68];
  const int t  = threadIdx.x;
  const int bm = by * 64, bn = bx * 64;
  const int lr = t >> 2, lq = t & 3;
  const int bkr = t >> 4, bnq = t & 15;
  const int tx = t & 15, ty = t >> 4;
  const float* Aptr = sl.A + (long long)(bm + lr) * sl.lda + lq * 4;
  const float* Bt   = sl.B + (long long)(bn + lr) * sl.ldb + lq * 4;
  const float* Bn   = sl.B + (long long)bkr * sl.ldb + bn + bnq * 4;
  float acc[4][4] = {};
  float4 a0, a1, b0, b1;

  auto loadg = [&](int k0) {
    a0 = *(const float4*)(Aptr + k0);
    a1 = *(const float4*)(Aptr + k0 + 16);
    if (TRANSB) { b0 = *(const float4*)(Bt + k0); b1 = *(const float4*)(Bt + k0 + 16); }
    else { b0 = *(const float4*)(Bn + (long long)k0 * sl.ldb);
           b1 = *(const float4*)(Bn + (long long)(k0 + 16) * sl.ldb); }
  };
  auto stage = [&](int bf) {
    As[bf][lq*4+0][lr]=a0.x; As[bf][lq*4+1][lr]=a0.y; As[bf][lq*4+2][lr]=a0.z; As[bf][lq*4+3][lr]=a0.w;
    As[bf][lq*4+16][lr]=a1.x; As[bf][lq*4+17][lr]=a1.y; As[bf][lq*4+18][lr]=a1.z; As[bf][lq*4+19][lr]=a1.w;
    if (TRANSB) {
      Bs[bf][lq*4+0][lr]=b0.x; Bs[bf][lq*4+1][lr]=b0.y; Bs[bf][lq*4+2][lr]=b0.z; Bs[bf][lq*4+3][lr]=b0.w;
      Bs[bf][lq*4+16][lr]=b1.x; Bs[bf][lq*4+17][lr]=b1.y; Bs[bf][lq*4+18][lr]=b1.z; Bs[bf][lq*4+19][lr]=b1.w;
    } else {
      *(float4*)&Bs[bf][bkr][bnq*4]    = b0;
      *(float4*)&Bs[bf][bkr+16][bnq*4] = b1;
    }
  };
  auto compute = [&](int bf) {
    #pragma unroll
    for (int kk = 0; kk < 32; ++kk) {
      float4 a = *(const float4*)&As[bf][kk][ty*4];
      float4 b = *(const float4*)&Bs[bf][kk][tx*4];
      acc[0][0]+=a.x*b.x; acc[0][1]+=a.x*b.y; acc[0][2]+=a.x*b.z; acc[0][3]+=a.x*b.w;
      acc[1][0]+=a.y*b.x; acc[1][1]+=a.y*b.y; acc[1][2]+=a.y*b.z; acc[1][3]+=a.y*b.w;
      acc[2][0]+=a.z*b.x; acc[2][1]+=a.z*b.y; acc[2][2]+=a.z*b.z; acc[2][3]+=a.z*b.w;
      acc[3][0]+=a.w*b.x; acc[3][1]+=a.w*b.y; acc[3][2]+=a.w*b.z; acc[3][3]+=a.w*b.w;
    }
  };

  loadg(0); stage(0); __syncthreads();
  int cur = 0;
  for (int k0 = 32; k0 < K; k0 += 32) {
    loadg(k0);
    compute(cur);
    stage(cur ^ 1);
    __syncthreads();
    cur ^= 1;
  }
  compute(cur);

  #pragma unroll
  for (int i = 0; i < 4; ++i) {
    float4 v;
    float* vp = &v.x;
    #pragma unroll
    for (int j = 0; j < 4; ++j) {
      float q = acc[i][j] * sl.scale;
      if (sl.act == 1) q = leaky(q);
      else if (sl.act == 2) q = 1.f / (1.f + expf(-q));
      vp[j] = q;
    }
    *(float4*)&sl.C[(long long)(bm + ty*4 + i) * sl.ldc + bn + tx*4] = v;
  }
}

// ---------------- z@zT fused: sigmoid + symmetric store + BCE + tie counts ----------------
__global__ __launch_bounds__(256)
void zzt_fused(const float* __restrict__ zv, const float* __restrict__ labels,
               float* __restrict__ radj, SelState* st, unsigned* __restrict__ rowTies)
{
  const int bx = blockIdx.x, by = blockIdx.y;
  if (bx < by) return;
  __shared__ float As[2][32][68];
  __shared__ float Bs[2][32][68];
  __shared__ unsigned rt[64];
  __shared__ float red[256];
  const int t = threadIdx.x;
  if (t < 64) rt[t] = 0;
  const int bm = by * 64, bn = bx * 64;
  const int lr = t >> 2, lq = t & 3;
  const int tx = t & 15, ty = t >> 4;
  const float* Ap = zv + (long long)(bm + lr) * 256 + lq * 4;
  const float* Bp = zv + (long long)(bn + lr) * 256 + lq * 4;
  float acc[4][4] = {};
  float4 a0, a1, b0, b1;

  auto loadg = [&](int k0) {
    a0 = *(const float4*)(Ap + k0); a1 = *(const float4*)(Ap + k0 + 16);
    b0 = *(const float4*)(Bp + k0); b1 = *(const float4*)(Bp + k0 + 16);
  };
  auto stage = [&](int bf) {
    As[bf][lq*4+0][lr]=a0.x; As[bf][lq*4+1][lr]=a0.y; As[bf][lq*4+2][lr]=a0.z; As[bf][lq*4+3][lr]=a0.w;
    As[bf][lq*4+16][lr]=a1.x; As[bf][lq*4+17][lr]=a1.y; As[bf][lq*4+18][lr]=a1.z; As[bf][lq*4+19][lr]=a1.w;
    Bs[bf][lq*4+0][lr]=b0.x; Bs[bf][lq*4+1][lr]=b0.y; Bs[bf][lq*4+2][lr]=b0.z; Bs[bf][lq*4+3][lr]=b0.w;
    Bs[bf][lq*4+16][lr]=b1.x; Bs[bf][lq*4+17][lr]=b1.y; Bs[bf][lq*4+18][lr]=b1.z; Bs[bf][lq*4+19][lr]=b1.w;
  };
  auto compute = [&](int bf) {
    #pragma unroll
    for (int kk = 0; kk < 32; ++kk) {
      float4 a = *(const float4*)&As[bf][kk][ty*4];
      float4 b = *(const float4*)&Bs[bf][kk][tx*4];
      acc[0][0]+=a.x*b.x; acc[0][1]+=a.x*b.y; acc[0][2]+=a.x*b.z; acc[0][3]+=a.x*b.w;
      acc[1][0]+=a.y*b.x; acc[1][1]+=a.y*b.y; acc[1][2]+=a.y*b.z; acc[1][3]+=a.y*b.w;
      acc[2][0]+=a.z*b.x; acc[2][1]+=a.z*b.y; acc[2][2]+=a.z*b.z; acc[2][3]+=a.z*b.w;
      acc[3][0]+=a.w*b.x; acc[3][1]+=a.w*b.y; acc[3][2]+=a.w*b.z; acc[3][3]+=a.w*b.w;
    }
  };

  loadg(0); stage(0); __syncthreads();
  int cur = 0;
  for (int k0 = 32; k0 < 256; k0 += 32) {
    loadg(k0);
    compute(cur);
    stage(cur ^ 1);
    __syncthreads();
    cur ^= 1;
  }
  compute(cur);

  float o[4][4];
  #pragma unroll
  for (int i = 0; i < 4; ++i)
    #pragma unroll
    for (int j = 0; j < 4; ++j)
      o[i][j] = 1.f / (1.f + expf(-acc[i][j]));

  // stores: primary tile rows bm+ty*4+i, cols bn+tx*4+j; mirror if off-diagonal
  #pragma unroll
  for (int i = 0; i < 4; ++i)
    *(float4*)&radj[(long long)(bm + ty*4 + i) * NN + bn + tx*4] =
        make_float4(o[i][0], o[i][1], o[i][2], o[i][3]);
  if (bx > by) {
    #pragma unroll
    for (int j = 0; j < 4; ++j)
      *(float4*)&radj[(long long)(bn + tx*4 + j) * NN + bm + ty*4] =
          make_float4(o[0][j], o[1][j], o[2][j], o[3][j]);
  }

  // BCE + labSum + tie counts
  float s1 = 0.f, s0 = 0.f, slb = 0.f;
  unsigned myc1 = 0;
  unsigned c1row[4] = {0, 0, 0, 0};
  #pragma unroll
  for (int i = 0; i < 4; ++i) {
    const int gr = bm + ty*4 + i;
    float4 lbp = *(const float4*)&labels[(long long)gr * NN + bn + tx*4];
    const float* lp = &lbp.x;
    #pragma unroll
    for (int j = 0; j < 4; ++j) {
      const int gc = bn + tx*4 + j;
      float p = o[i][j];
      float e = expf(-p), l1p = log1pf(e);
      float lb = lp[j];
      s1 += lb * l1p;
      s0 += (1.f - lb) * (p + l1p);
      slb += lb;
      if ((bx > by || gc > gr) && __float_as_uint(p) == ONEB) { c1row[i]++; myc1++; }
    }
  }
  if (bx > by) {
    #pragma unroll
    for (int j = 0; j < 4; ++j) {
      const int gc = bn + tx*4 + j;
      float4 lbm = *(const float4*)&labels[(long long)gc * NN + bm + ty*4];
      const float* lp = &lbm.x;
      #pragma unroll
      for (int i = 0; i < 4; ++i) {
        float p = o[i][j];
        float e = expf(-p), l1p = log1pf(e);
        float lb = lp[i];
        s1 += lb * l1p;
        s0 += (1.f - lb) * (p + l1p);
        slb += lb;
      }
    }
  }
  #pragma unroll
  for (int i = 0; i < 4; ++i)
    if (c1row[i]) atomicAdd(&rt[ty*4 + i], c1row[i]);

  __syncthreads();
  red[t] = s1; __syncthreads();
  for (int s = 128; s > 0; s >>= 1) { if (t < s) red[t] += red[t + s]; __syncthreads(); }
  if (t == 0) atomicAdd(&st->sum1, (double)red[0]);
  __syncthreads();
  red[t] = s0; __syncthreads();
  for (int s = 128; s > 0; s >>= 1) { if (t < s) red[t] += red[t + s]; __syncthreads(); }
  if (t == 0) atomicAdd(&st->sum0, (double)red[0]);
  __syncthreads();
  red[t] = slb; __syncthreads();
  for (int s = 128; s > 0; s >>= 1) { if (t < s) red[t] += red[t + s]; __syncthreads(); }
  if (t == 0) atomicAdd(&st->labSum, (double)red[0]);
  __syncthreads();
  red[t] = (float)myc1; __syncthreads();
  for (int s = 128; s > 0; s >>= 1) { if (t < s) red[t] += red[t + s]; __syncthreads(); }
  if (t == 0 && red[0] > 0.f) atomicAdd(&st->cnt1, (unsigned)red[0]);
  if (t < 64 && rt[t]) atomicAdd(&rowTies[bm + t], rt[t]);
}

// ---------------- ELL build ----------------
__global__ __launch_bounds__(64)
void build_ell(EB eb)
{
  const int b = blockIdx.y, row = blockIdx.x, lane = threadIdx.x;
  const float* adj = eb.adj[b];
  int base = 0;
  for (int c0 = 0; c0 < NN; c0 += 64) {
    float v = adj[(long long)row * NN + c0 + lane];
    unsigned long long m = __ballot(v != 0.0f);
    if (v != 0.0f) {
      int pos = base + __popcll(m & ((1ull << lane) - 1ull));
      if (pos < CAP) { eb.col[b][row * CAP + pos] = c0 + lane; eb.val[b][row * CAP + pos] = v; }
    }
    base += __popcll(m);
  }
  if (lane == 0) eb.cnt[b][row] = base > CAP ? CAP : base;
}

// ---------------- batched spMM over 512 cols ----------------
__global__ __launch_bounds__(256)
void spmm_leaky(SB sb)
{
  const int b = blockIdx.y, row = blockIdx.x, t = threadIdx.x;
  __shared__ int   sc[CAP];
  __shared__ float sv[CAP];
  __shared__ int   n;
  if (t == 0) n = sb.cnt[b][row];
  if (t < CAP) { sc[t] = sb.col[b][row * CAP + t]; sv[t] = sb.val[b][row * CAP + t]; }
  __syncthreads();
  const int m = n;
  const float* S = sb.S[b];
  float a0 = 0.f, a1 = 0.f;
  for (int i = 0; i < m; ++i) {
    const float* Sr = S + (long long)sc[i] * 512;
    float v = sv[i];
    a0 += v * Sr[t];
    a1 += v * Sr[t + 256];
  }
  sb.out[b][(long long)row * 512 + t]       = leaky(a0);
  sb.out[b][(long long)row * 512 + t + 256] = leaky(a1);
}

// ---------------- wave softmax: 4 rows/block, 1 wave/row, no barriers ----------------
__global__ __launch_bounds__(256)
void softmax256(float* __restrict__ x)
{
  const int row = blockIdx.x * 4 + (threadIdx.x >> 6);
  const int l = threadIdx.x & 63;
  float4 v = *(float4*)&x[(long long)row * 256 + l * 4];
  float m = fmaxf(fmaxf(v.x, v.y), fmaxf(v.z, v.w));
  for (int s = 32; s; s >>= 1) m = fmaxf(m, __shfl_xor(m, s));
  float e0 = expf(v.x - m), e1 = expf(v.y - m), e2 = expf(v.z - m), e3 = expf(v.w - m);
  float sm = e0 + e1 + e2 + e3;
  for (int s = 32; s; s >>= 1) sm += __shfl_xor(sm, s);
  float inv = 1.f / sm;
  *(float4*)&x[(long long)row * 256 + l * 4] = make_float4(e0*inv, e1*inv, e2*inv, e3*inv);
}

// ---------------- z = eps*exp(0.5*lv)+mu, fused with KLD row partial ----------------
__global__ __launch_bounds__(256)
void z_kld(const float* __restrict__ eps, const float* __restrict__ mpo,
           const float* __restrict__ mpr, float* __restrict__ z, SelState* st)
{
  __shared__ float red[256];
  const int row = blockIdx.x, c = threadIdx.x;
  float mu = mpo[row * 512 + c], lv = mpo[row * 512 + 256 + c];
  z[row * 256 + c] = eps[row * 256 + c] * expf(0.5f * lv) + mu;
  float mu2 = mpr[row * 512 + c], lv2 = mpr[row * 512 + 256 + c];
  float d = mu2 - mu, dl = lv - lv2;
  red[c] = d * d * expf(-lv2) + expf(dl) - 1.f - dl;
  __syncthreads();
  for (int s = 128; s > 0; s >>= 1) { if (c < s) red[c] += red[c + s]; __syncthreads(); }
  if (c == 0) atomicAdd(&st->kldSum, (double)red[0]);
}

// ---------------- select: fast path (cnt1>=512 -> T=1.0f) else full radix fallback ----------------
__global__ __launch_bounds__(1024)
void select_kernel(const float* __restrict__ radj, SelState* st, unsigned* __restrict__ rowTies)
{
  const int tid = threadIdx.x;
  if (st->cnt1 >= (unsigned)TOPK) {
    if (tid == 0) { st->T = ONEB; st->r = TOPK; }
    return;
  }
  __shared__ unsigned hist[256];
  __shared__ unsigned prefix_s, rem_s;
  unsigned prefix = 0, rem = TOPK;
  for (int pass = 0; pass < 4; ++pass) {
    const int shift = 24 - 8 * pass;
    const unsigned mask = pass ? (0xFFFFFFFFu << (32 - 8 * pass)) : 0u;
    if (tid < 256) hist[tid] = 0;
    __syncthreads();
    for (int idx = tid; idx < TOTE; idx += 1024) {
      int i = idx >> 11, j = idx & 2047;
      if (j <= i) continue;
      unsigned b = __float_as_uint(radj[idx]);
      if ((b & mask) == prefix) atomicAdd(&hist[(b >> shift) & 255], 1u);
    }
    __syncthreads();
    if (tid == 0) {
      unsigned cg = 0;
      for (int bb = 255; bb >= 0; --bb) {
        unsigned c = hist[bb];
        if (cg + c >= rem) { prefix |= ((unsigned)bb) << shift; rem -= cg; break; }
        cg += c;
      }
      prefix_s = prefix; rem_s = rem;
    }
    __syncthreads();
    prefix = prefix_s; rem = rem_s;
  }
  if (tid == 0) { st->T = prefix; st->r = rem; }
  for (int r = tid; r < NN; r += 1024) rowTies[r] = 0;
  __syncthreads();
  for (int idx = tid; idx < TOTE; idx += 1024) {
    int i = idx >> 11, j = idx & 2047;
    if (j <= i) continue;
    if (__float_as_uint(radj[idx]) == prefix) atomicAdd(&rowTies[i], 1u);
  }
}

// ---------------- cut row: prefix-scan rowTies to find row containing the r-th tie ----------------
__global__ __launch_bounds__(256)
void cut_row(const unsigned* __restrict__ rowTies, SelState* st)
{
  __shared__ unsigned ps[256];
  const int t = threadIdx.x;
  unsigned loc[8], s = 0;
  for (int i = 0; i < 8; ++i) { loc[i] = rowTies[t * 8 + i]; s += loc[i]; }
  ps[t] = s; __syncthreads();
  for (int sh = 1; sh < 256; sh <<= 1) {
    unsigned v = (t >= sh) ? ps[t - sh] : 0; __syncthreads();
    ps[t] += v; __syncthreads();
  }
  const unsigned r = st->r;
  const unsigned exc = ps[t] - s;
  if (r > exc && r <= ps[t]) {
    unsigned cum = exc;
    for (int i = 0; i < 8; ++i) {
      if (r <= cum + loc[i]) { st->tieRow = t * 8 + i; st->tieRem = r - cum; break; }
      cum += loc[i];
    }
  }
}

// ---------------- find exact threshold column within the cut row (one wave, ballot) ----------------
__global__ __launch_bounds__(64)
void find_col(const float* __restrict__ radj, SelState* st)
{
  const int R = (int)st->tieRow;
  const unsigned rem = st->tieRem, T = st->T;
  unsigned base = 0;
  for (int c0 = R + 1; c0 < NN; c0 += 64) {
    const int c = c0 + (int)threadIdx.x;
    bool f = (c < NN) && (__float_as_uint(radj[(long long)R * NN + c]) == T);
    unsigned long long m = __ballot(f);
    unsigned cnt = (unsigned)__popcll(m);
    if (base + cnt >= rem) {
      if (f) {
        unsigned rank = (unsigned)__popcll(m & ((1ull << threadIdx.x) - 1ull)) + 1u;
        if (base + rank == rem) st->Ithr = (unsigned)(R * NN + c);
      }
      return;
    }
    base += cnt;
  }
}

__global__ __launch_bounds__(256)
void collect_kernel(const float* __restrict__ radj, SelState* st,
                    unsigned* __restrict__ cand_bits, unsigned* __restrict__ cand_idx)
{
  const int row = blockIdx.x;
  const unsigned T = st->T, It = st->Ithr;
  for (int c = row + 1 + threadIdx.x; c < NN; c += 256) {
    int idx = row * NN + c;
    unsigned b = __float_as_uint(radj[idx]);
    if (b > T || (b == T && (unsigned)idx <= It)) {
      unsigned p = atomicAdd(&st->cTotal, 1u);
      if (p < (unsigned)TOPK) { cand_bits[p] = b; cand_idx[p] = (unsigned)idx; }
    }
  }
}

__global__ __launch_bounds__(512)
void rank_sort(const unsigned* __restrict__ cand_bits,
               const unsigned* __restrict__ cand_idx, unsigned* __restrict__ ord)
{
  __shared__ unsigned vb[512], vi[512];
  const int t = threadIdx.x;
  vb[t] = cand_bits[t]; vi[t] = cand_idx[t];
  __syncthreads();
  unsigned b = vb[t], id = vi[t];
  int rank = 0;
  for (int u = 0; u < 512; ++u)
    rank += (vb[u] > b) || (vb[u] == b && vi[u] < id);
  ord[rank] = id;
}

__global__ __launch_bounds__(256)
void gather_rel(const unsigned* __restrict__ ord, const float* __restrict__ ns2,
                float* __restrict__ out)
{
  const int r = blockIdx.x, c = threadIdx.x;
  unsigned id = ord[r];
  int a = id >> 11, b = id & 2047;
  out[r * 256 + c] = ns2[a * 256 + c] + ns2[b * 256 + c];
}

__global__ __launch_bounds__(512)
void finalize_kernel(const SelState* st, float* __restrict__ out)
{
  const int t = threadIdx.x;
  out[TOPK * H2D + t] = 0.0f;                 // rel_mask: all False
  if (t == 0) {
    double s   = st->labSum;
    double nn  = (double)NN * NN;
    double pw  = (nn - s + NN) / (s - NN + 0.01);
    double nrm = nn / (nn - s + NN);
    out[TOPK * H2D + TOPK + 0] = (float)(nrm * (pw * st->sum1 + st->sum0) / nn);
    out[TOPK * H2D + TOPK + 1] = (float)(0.5 * st->kldSum / nn);
  }
}

} // namespace

extern "C" void kernel_launch(void* const* d_in, const int* in_sizes, int n_in,
                              void* d_out, int out_size, void* d_ws, size_t ws_size,
                              hipStream_t stream)
{
  (void)in_sizes; (void)n_in; (void)out_size; (void)ws_size;
  const float* ns_emb    = (const float*)d_in[0];
  const float* adj       = (const float*)d_in[1];
  const float* adj_prior = (const float*)d_in[2];
  const float* cond      = (const float*)d_in[3];
  const float* labels    = (const float*)d_in[4];
  const float* eps       = (const float*)d_in[5];
  const float* W_map     = (const float*)d_in[6];
  const float* Wb[2][7];
  for (int k = 0; k < 14; ++k) Wb[k / 7][k % 7] = (const float*)d_in[7 + k];
  float* out = (float*)d_out;

  // ---- workspace ----
  char* w = (char*)d_ws;
  SelState* st      = (SelState*)w;          w += 256;
  unsigned* rowTies = (unsigned*)w;          w += NN * 4;     // memset with st
  unsigned* cand_bits = (unsigned*)w;        w += TOPK * 4;
  unsigned* cand_idx  = (unsigned*)w;        w += TOPK * 4;
  unsigned* ord       = (unsigned*)w;        w += TOPK * 4;
  w = (char*)(((uintptr_t)w + 255) & ~(uintptr_t)255);
  int* ellCnt[2]; int* ellCol[2]; float* ellVal[2];
  for (int b = 0; b < 2; ++b) {
    ellCnt[b] = (int*)w;   w += NN * 4;
    ellCol[b] = (int*)w;   w += (size_t)NN * CAP * 4;
    ellVal[b] = (float*)w; w += (size_t)NN * CAP * 4;
  }
  const long long NNH1 = (long long)NN * H1D;
  const long long LCH  = (long long)LCD * H1D;
  float* AR = (float*)w;  w += (size_t)(6 * NNH1 + 4 * LCH) * 4;
  float* mulv[2];
  mulv[0] = (float*)w;    w += (size_t)NNH1 * 4;
  mulv[1] = (float*)w;    w += (size_t)NNH1 * 4;
  float* zb  = (float*)w; w += (size_t)NN * H2D * 4;
  float* ns2 = (float*)w; w += (size_t)NN * H2D * 4;

  // arena aliases (S->Q->H2 share; H->O share; SC->T2 share; radj over all at decode)
  float* S[2]  = { AR,          AR + NNH1 };
  float* Q[2]  = { AR,          AR + NNH1 };
  float* H[2]  = { AR + 2*NNH1, AR + 3*NNH1 };
  float* O[2]  = { AR + 2*NNH1, AR + 3*NNH1 };
  float* Kb[2] = { AR + 4*NNH1,         AR + 4*NNH1 + LCH };
  float* Vb[2] = { AR + 4*NNH1 + 2*LCH, AR + 4*NNH1 + 3*LCH };
  float* SC    =   AR + 4*NNH1 + 4*LCH;
  float* T2[2] = { SC,          SC + NNH1 };
  float* H2[2] = { AR,          AR + NNH1 };
  float* radj  =   AR;

  hipMemsetAsync(st, 0, 256 + NN * 4, stream);   // SelState + rowTies

  { // ELL build
    EB eb{};
    eb.adj[0] = adj; eb.adj[1] = adj_prior;
    for (int b = 0; b < 2; ++b) { eb.cnt[b]=ellCnt[b]; eb.col[b]=ellCol[b]; eb.val[b]=ellVal[b]; }
    build_ell<<<dim3(NN, 2), 64, 0, stream>>>(eb);
  }

  auto mkslot = [](const float* A, const float* B, float* C, int lda, int ldb, int ldc,
                   int nshift, int act, float scale) {
    Slot s; s.A=A; s.B=B; s.C=C; s.lda=lda; s.ldb=ldb; s.ldc=ldc;
    s.nshift=nshift; s.act=act; s.scale=scale; return s;
  };

  { // phase 1: S[2] (leaky), K/V[4], ns2 (leaky) — all K=768 inputs
    Launch P{};
    P.s[0] = mkslot(ns_emb, Wb[0][0], S[0], FIN, H1D, H1D, 3, 1, 1.f);
    P.s[1] = mkslot(ns_emb, Wb[1][0], S[1], FIN, H1D, H1D, 3, 1, 1.f);
    P.s[2] = mkslot(cond,   Wb[0][2], Kb[0], FIN, H1D, H1D, 3, 0, 1.f);
    P.s[3] = mkslot(cond,   Wb[1][2], Kb[1], FIN, H1D, H1D, 3, 0, 1.f);
    P.s[4] = mkslot(cond,   Wb[0][3], Vb[0], FIN, H1D, H1D, 3, 0, 1.f);
    P.s[5] = mkslot(cond,   Wb[1][3], Vb[1], FIN, H1D, H1D, 3, 0, 1.f);
    P.s[6] = mkslot(ns_emb, W_map,    ns2,  FIN, H2D, H2D, 2, 1, 1.f);
    int ze[8] = {256, 512, 544, 576, 608, 640, 768, 768};
    for (int i = 0; i < 8; ++i) P.zend[i] = ze[i];
    mega_gemm<0><<<dim3(768), 256, 0, stream>>>(P, FIN);
  }
  { // spmm1: H = leaky(adj @ S)
    SB sb{};
    for (int br = 0; br < 2; ++br) { sb.cnt[br]=ellCnt[br]; sb.col[br]=ellCol[br];
      sb.val[br]=ellVal[br]; sb.S[br]=S[br]; sb.out[br]=H[br]; }
    spmm_leaky<<<dim3(NN, 2), 256, 0, stream>>>(sb);
  }
  { // Q = H @ Wq
    Launch P{};
    P.s[0] = mkslot(H[0], Wb[0][1], Q[0], H1D, H1D, H1D, 3, 0, 1.f);
    P.s[1] = mkslot(H[1], Wb[1][1], Q[1], H1D, H1D, H1D, 3, 0, 1.f);
    int ze[8] = {256, 512, 512, 512, 512, 512, 512, 512};
    for (int i = 0; i < 8; ++i) P.zend[i] = ze[i];
    mega_gemm<0><<<dim3(512), 256, 0, stream>>>(P, H1D);
  }
  { // scores = Q_hd @ K_hd^T / 16
    Launch P{};
    for (int br = 0; br < 2; ++br) for (int hd = 0; hd < 2; ++hd) {
      int z = br * 2 + hd;
      P.s[z] = mkslot(Q[br] + hd*256, Kb[br] + hd*256, SC + (long long)z*NN*256,
                      H1D, H1D, 256, 2, 0, 0.0625f);
    }
    int ze[8] = {128, 256, 384, 512, 512, 512, 512, 512};
    for (int i = 0; i < 8; ++i) P.zend[i] = ze[i];
    mega_gemm<1><<<dim3(512), 256, 0, stream>>>(P, 256);
  }
  softmax256<<<dim3(NN), 256, 0, stream>>>(SC);
  { // O = attn @ V_hd
    Launch P{};
    for (int br = 0; br < 2; ++br) for (int hd = 0; hd < 2; ++hd) {
      int z = br * 2 + hd;
      P.s[z] = mkslot(SC + (long long)z*NN*256, Vb[br] + hd*256, O[br] + hd*256,
                      256, H1D, H1D, 2, 0, 1.f);
    }
    int ze[8] = {128, 256, 384, 512, 512, 512, 512, 512};
    for (int i = 0; i < 8; ++i) P.zend[i] = ze[i];
    mega_gemm<0><<<dim3(512), 256, 0, stream>>>(P, 256);
  }
  { // H2 = O @ Wo
    Launch P{};
    P.s[0] = mkslot(O[0], Wb[0][4], H2[0], H1D, H1D, H1D, 3, 0, 1.f);
    P.s[1] = mkslot(O[1], Wb[1][4], H2[1], H1D, H1D, H1D, 3, 0, 1.f);
    int ze[8] = {256, 512, 512, 512, 512, 512, 512, 512};
    for (int i = 0; i < 8; ++i) P.zend[i] = ze[i];
    mega_gemm<0><<<dim3(512), 256, 0, stream>>>(P, H1D);
  }
  { // T2 = leaky(H2 @ [Wmu|Wvar])
    Launch P{};
    for (int br = 0; br < 2; ++br) {
      P.s[br]   = mkslot(H2[br], Wb[br][5], T2[br],       H1D, H2D, H1D, 2, 1, 1.f);
      P.s[2+br] = mkslot(H2[br], Wb[br][6], T2[br] + H2D, H1D, H2D, H1D, 2, 1, 1.f);
    }
    int ze[8] = {128, 256, 384, 512, 512, 512, 512, 512};
    for (int i = 0; i < 8; ++i) P.zend[i] = ze[i];
    mega_gemm<0><<<dim3(512), 256, 0, stream>>>(P, H1D);
  }
  { // spmm2: mulv = leaky(adj @ T2)
    SB sb{};
    for (int br = 0; br < 2; ++br) { sb.cnt[br]=ellCnt[br]; sb.col[br]=ellCol[br];
      sb.val[br]=ellVal[br]; sb.S[br]=T2[br]; sb.out[br]=mulv[br]; }
    spmm_leaky<<<dim3(NN, 2), 256, 0, stream>>>(sb);
  }

  z_kld<<<dim3(NN), 256, 0, stream>>>(eps, mulv[0], mulv[1], zb, st);
  zzt_fused<<<dim3(32, 32), 256, 0, stream>>>(zb, labels, radj, st, rowTies);

  select_kernel<<<dim3(1), 1024, 0, stream>>>(radj, st, rowTies);
  cut_row<<<dim3(1), 256, 0, stream>>>(rowTies, st);
  find_col<<<dim3(1), 64, 0, stream>>>(radj, st);
  collect_kernel<<<dim3(NN), 256, 0, stream>>>(radj, st, cand_bits, cand_idx);
  rank_sort<<<dim3(1), 512, 0, stream>>>(cand_bits, cand_idx, ord);
  gather_rel<<<dim3(TOPK), 256, 0, stream>>>(ord, ns2, out);
  finalize_kernel<<<dim3(1), 512, 0, stream>>>(st, out);
}

// Round 8
// 502.962 us; speedup vs baseline: 6.5837x; 1.1840x over previous
//
#include <hip/hip_runtime.h>
#include <math.h>
#include <stdint.h>

// GCNModelVAE forward on MI355X — round 8.
// Round-7 counters: KT=32 mega_gemm = VGPR 144, occupancy 10.9%, VALU 34%,
// phase-1 FETCH 70MB (3x over-fetch, A-slabs refetched once per XCD), 718 GB/s
// => HBM-latency-bound. Fixes:
//  - revert GEMM core to KT=16 double-buffer (round-2-proven: VGPR 36, VALU 46%)
//  - XCD-chunked blockIdx swizzle (T1): wg = (bid&7)*(G/8) + (bid>>3), all grids %8==0
// Everything else (fused zzT+BCE+ties, fast-path select, spmm, tail) unchanged.

namespace {

constexpr int NN   = 2048;
constexpr int FIN  = 768;
constexpr int H1D  = 512;
constexpr int H2D  = 256;
constexpr int LCD  = 256;
constexpr int TOPK = 512;
constexpr int TOTE = NN * NN;
constexpr int CAP  = 96;
constexpr unsigned ONEB = 0x3F800000u;   // bits of 1.0f

struct SelState {
  unsigned cnt1, T, r, tieRow, tieRem, Ithr, cTotal, pad;
  double sum1, sum0, labSum, kldSum;
};

struct Slot  { const float* A; const float* B; float* C;
               int lda, ldb, ldc, nshift, act; float scale; };
struct Launch{ Slot s[8]; int zend[8]; };
struct EB { const float* adj[2]; int* cnt[2]; int* col[2]; float* val[2]; };
struct SB { const int* cnt[2]; const int* col[2]; const float* val[2];
            const float* S[2]; float* out[2]; };

__device__ __forceinline__ float leaky(float v) { return v >= 0.f ? v : 0.01f * v; }

// ------- mega GEMM: 64x64 tile, 4x4 micro, KT=16 double-buffered, XCD swizzle -------
// Up to 8 independent (A,B,C) slots per launch; slot decoded from swizzled block id.
// All dims: M%64==0, N%64==0, K%16==0, leading dims %4==0. Grid size must be %8==0.
template<int TRANSB>
__global__ __launch_bounds__(256)
void mega_gemm(Launch P, int K)
{
  const int G = gridDim.x;
  const int bid = blockIdx.x;
  const int wg = (bid & 7) * (G >> 3) + (bid >> 3);   // XCD-chunked swizzle (bijective, G%8==0)
  int z = 0, start = 0;
  #pragma unroll
  for (int i = 0; i < 7; ++i)
    if (wg >= P.zend[i]) { z = i + 1; start = P.zend[i]; }
  Slot sl = P.s[0];
  #pragma unroll
  for (int i = 1; i < 8; ++i) if (z == i) sl = P.s[i];
  const int local = wg - start;
  const int by = local >> sl.nshift;
  const int bx = local & ((1 << sl.nshift) - 1);

  __shared__ float As[2][16][68];
  __shared__ float Bs[2][16][68];
  const int t  = threadIdx.x;
  const int bm = by * 64, bn = bx * 64;
  const int lr = t >> 2, lq = t & 3;        // 64 rows x 4 k-quads staging
  const int bkr = t >> 4, bnq = t & 15;     // 16 k x 16 n-quads (B no-trans)
  const int tx = t & 15, ty = t >> 4;
  const float* Aptr = sl.A + (long long)(bm + lr) * sl.lda + lq * 4;
  const float* Bt   = sl.B + (long long)(bn + lr) * sl.ldb + lq * 4;
  const float* Bn   = sl.B + (long long)bkr * sl.ldb + bn + bnq * 4;
  float acc[4][4] = {};
  float4 av, bv;

  auto loadg = [&](int k0) {
    av = *(const float4*)(Aptr + k0);
    bv = TRANSB ? *(const float4*)(Bt + k0)
                : *(const float4*)(Bn + (long long)k0 * sl.ldb);
  };
  auto stage = [&](int bf) {
    As[bf][lq*4+0][lr]=av.x; As[bf][lq*4+1][lr]=av.y; As[bf][lq*4+2][lr]=av.z; As[bf][lq*4+3][lr]=av.w;
    if (TRANSB) {
      Bs[bf][lq*4+0][lr]=bv.x; Bs[bf][lq*4+1][lr]=bv.y; Bs[bf][lq*4+2][lr]=bv.z; Bs[bf][lq*4+3][lr]=bv.w;
    } else {
      *(float4*)&Bs[bf][bkr][bnq*4] = bv;
    }
  };
  auto compute = [&](int bf) {
    #pragma unroll
    for (int kk = 0; kk < 16; ++kk) {
      float4 a = *(const float4*)&As[bf][kk][ty*4];
      float4 b = *(const float4*)&Bs[bf][kk][tx*4];
      acc[0][0]+=a.x*b.x; acc[0][1]+=a.x*b.y; acc[0][2]+=a.x*b.z; acc[0][3]+=a.x*b.w;
      acc[1][0]+=a.y*b.x; acc[1][1]+=a.y*b.y; acc[1][2]+=a.y*b.z; acc[1][3]+=a.y*b.w;
      acc[2][0]+=a.z*b.x; acc[2][1]+=a.z*b.y; acc[2][2]+=a.z*b.z; acc[2][3]+=a.z*b.w;
      acc[3][0]+=a.w*b.x; acc[3][1]+=a.w*b.y; acc[3][2]+=a.w*b.z; acc[3][3]+=a.w*b.w;
    }
  };

  loadg(0); stage(0); __syncthreads();
  int cur = 0;
  for (int k0 = 16; k0 < K; k0 += 16) {
    loadg(k0);
    compute(cur);
    stage(cur ^ 1);
    __syncthreads();
    cur ^= 1;
  }
  compute(cur);

  #pragma unroll
  for (int i = 0; i < 4; ++i) {
    float4 v;
    float* vp = &v.x;
    #pragma unroll
    for (int j = 0; j < 4; ++j) {
      float q = acc[i][j] * sl.scale;
      if (sl.act == 1) q = leaky(q);
      else if (sl.act == 2) q = 1.f / (1.f + expf(-q));
      vp[j] = q;
    }
    *(float4*)&sl.C[(long long)(bm + ty*4 + i) * sl.ldc + bn + tx*4] = v;
  }
}

// ---------------- z@zT fused: sigmoid + symmetric store + BCE + tie counts ----------------
__global__ __launch_bounds__(256)
void zzt_fused(const float* __restrict__ zv, const float* __restrict__ labels,
               float* __restrict__ radj, SelState* st, unsigned* __restrict__ rowTies)
{
  const int bx = blockIdx.x, by = blockIdx.y;
  if (bx < by) return;
  __shared__ float As[2][32][68];
  __shared__ float Bs[2][32][68];
  __shared__ unsigned rt[64];
  __shared__ float red[256];
  const int t = threadIdx.x;
  if (t < 64) rt[t] = 0;
  const int bm = by * 64, bn = bx * 64;
  const int lr = t >> 2, lq = t & 3;
  const int tx = t & 15, ty = t >> 4;
  const float* Ap = zv + (long long)(bm + lr) * 256 + lq * 4;
  const float* Bp = zv + (long long)(bn + lr) * 256 + lq * 4;
  float acc[4][4] = {};
  float4 a0, a1, b0, b1;

  auto loadg = [&](int k0) {
    a0 = *(const float4*)(Ap + k0); a1 = *(const float4*)(Ap + k0 + 16);
    b0 = *(const float4*)(Bp + k0); b1 = *(const float4*)(Bp + k0 + 16);
  };
  auto stage = [&](int bf) {
    As[bf][lq*4+0][lr]=a0.x; As[bf][lq*4+1][lr]=a0.y; As[bf][lq*4+2][lr]=a0.z; As[bf][lq*4+3][lr]=a0.w;
    As[bf][lq*4+16][lr]=a1.x; As[bf][lq*4+17][lr]=a1.y; As[bf][lq*4+18][lr]=a1.z; As[bf][lq*4+19][lr]=a1.w;
    Bs[bf][lq*4+0][lr]=b0.x; Bs[bf][lq*4+1][lr]=b0.y; Bs[bf][lq*4+2][lr]=b0.z; Bs[bf][lq*4+3][lr]=b0.w;
    Bs[bf][lq*4+16][lr]=b1.x; Bs[bf][lq*4+17][lr]=b1.y; Bs[bf][lq*4+18][lr]=b1.z; Bs[bf][lq*4+19][lr]=b1.w;
  };
  auto compute = [&](int bf) {
    #pragma unroll
    for (int kk = 0; kk < 32; ++kk) {
      float4 a = *(const float4*)&As[bf][kk][ty*4];
      float4 b = *(const float4*)&Bs[bf][kk][tx*4];
      acc[0][0]+=a.x*b.x; acc[0][1]+=a.x*b.y; acc[0][2]+=a.x*b.z; acc[0][3]+=a.x*b.w;
      acc[1][0]+=a.y*b.x; acc[1][1]+=a.y*b.y; acc[1][2]+=a.y*b.z; acc[1][3]+=a.y*b.w;
      acc[2][0]+=a.z*b.x; acc[2][1]+=a.z*b.y; acc[2][2]+=a.z*b.z; acc[2][3]+=a.z*b.w;
      acc[3][0]+=a.w*b.x; acc[3][1]+=a.w*b.y; acc[3][2]+=a.w*b.z; acc[3][3]+=a.w*b.w;
    }
  };

  loadg(0); stage(0); __syncthreads();
  int cur = 0;
  for (int k0 = 32; k0 < 256; k0 += 32) {
    loadg(k0);
    compute(cur);
    stage(cur ^ 1);
    __syncthreads();
    cur ^= 1;
  }
  compute(cur);

  float o[4][4];
  #pragma unroll
  for (int i = 0; i < 4; ++i)
    #pragma unroll
    for (int j = 0; j < 4; ++j)
      o[i][j] = 1.f / (1.f + expf(-acc[i][j]));

  #pragma unroll
  for (int i = 0; i < 4; ++i)
    *(float4*)&radj[(long long)(bm + ty*4 + i) * NN + bn + tx*4] =
        make_float4(o[i][0], o[i][1], o[i][2], o[i][3]);
  if (bx > by) {
    #pragma unroll
    for (int j = 0; j < 4; ++j)
      *(float4*)&radj[(long long)(bn + tx*4 + j) * NN + bm + ty*4] =
          make_float4(o[0][j], o[1][j], o[2][j], o[3][j]);
  }

  // BCE + labSum + tie counts
  float s1 = 0.f, s0 = 0.f, slb = 0.f;
  unsigned myc1 = 0;
  unsigned c1row[4] = {0, 0, 0, 0};
  #pragma unroll
  for (int i = 0; i < 4; ++i) {
    const int gr = bm + ty*4 + i;
    float4 lbp = *(const float4*)&labels[(long long)gr * NN + bn + tx*4];
    const float* lp = &lbp.x;
    #pragma unroll
    for (int j = 0; j < 4; ++j) {
      const int gc = bn + tx*4 + j;
      float p = o[i][j];
      float e = expf(-p), l1p = log1pf(e);
      float lb = lp[j];
      s1 += lb * l1p;
      s0 += (1.f - lb) * (p + l1p);
      slb += lb;
      if ((bx > by || gc > gr) && __float_as_uint(p) == ONEB) { c1row[i]++; myc1++; }
    }
  }
  if (bx > by) {
    #pragma unroll
    for (int j = 0; j < 4; ++j) {
      float4 lbm = *(const float4*)&labels[(long long)(bn + tx*4 + j) * NN + bm + ty*4];
      const float* lp = &lbm.x;
      #pragma unroll
      for (int i = 0; i < 4; ++i) {
        float p = o[i][j];
        float e = expf(-p), l1p = log1pf(e);
        float lb = lp[i];
        s1 += lb * l1p;
        s0 += (1.f - lb) * (p + l1p);
        slb += lb;
      }
    }
  }
  #pragma unroll
  for (int i = 0; i < 4; ++i)
    if (c1row[i]) atomicAdd(&rt[ty*4 + i], c1row[i]);

  __syncthreads();
  red[t] = s1; __syncthreads();
  for (int s = 128; s > 0; s >>= 1) { if (t < s) red[t] += red[t + s]; __syncthreads(); }
  if (t == 0) atomicAdd(&st->sum1, (double)red[0]);
  __syncthreads();
  red[t] = s0; __syncthreads();
  for (int s = 128; s > 0; s >>= 1) { if (t < s) red[t] += red[t + s]; __syncthreads(); }
  if (t == 0) atomicAdd(&st->sum0, (double)red[0]);
  __syncthreads();
  red[t] = slb; __syncthreads();
  for (int s = 128; s > 0; s >>= 1) { if (t < s) red[t] += red[t + s]; __syncthreads(); }
  if (t == 0) atomicAdd(&st->labSum, (double)red[0]);
  __syncthreads();
  red[t] = (float)myc1; __syncthreads();
  for (int s = 128; s > 0; s >>= 1) { if (t < s) red[t] += red[t + s]; __syncthreads(); }
  if (t == 0 && red[0] > 0.f) atomicAdd(&st->cnt1, (unsigned)red[0]);
  if (t < 64 && rt[t]) atomicAdd(&rowTies[bm + t], rt[t]);
}

// ---------------- ELL build ----------------
__global__ __launch_bounds__(64)
void build_ell(EB eb)
{
  const int b = blockIdx.y, row = blockIdx.x, lane = threadIdx.x;
  const float* adj = eb.adj[b];
  int base = 0;
  for (int c0 = 0; c0 < NN; c0 += 64) {
    float v = adj[(long long)row * NN + c0 + lane];
    unsigned long long m = __ballot(v != 0.0f);
    if (v != 0.0f) {
      int pos = base + __popcll(m & ((1ull << lane) - 1ull));
      if (pos < CAP) { eb.col[b][row * CAP + pos] = c0 + lane; eb.val[b][row * CAP + pos] = v; }
    }
    base += __popcll(m);
  }
  if (lane == 0) eb.cnt[b][row] = base > CAP ? CAP : base;
}

// ---------------- batched spMM over 512 cols ----------------
__global__ __launch_bounds__(256)
void spmm_leaky(SB sb)
{
  const int b = blockIdx.y, row = blockIdx.x, t = threadIdx.x;
  __shared__ int   sc[CAP];
  __shared__ float sv[CAP];
  __shared__ int   n;
  if (t == 0) n = sb.cnt[b][row];
  if (t < CAP) { sc[t] = sb.col[b][row * CAP + t]; sv[t] = sb.val[b][row * CAP + t]; }
  __syncthreads();
  const int m = n;
  const float* S = sb.S[b];
  float a0 = 0.f, a1 = 0.f;
  for (int i = 0; i < m; ++i) {
    const float* Sr = S + (long long)sc[i] * 512;
    float v = sv[i];
    a0 += v * Sr[t];
    a1 += v * Sr[t + 256];
  }
  sb.out[b][(long long)row * 512 + t]       = leaky(a0);
  sb.out[b][(long long)row * 512 + t + 256] = leaky(a1);
}

// ---------------- wave softmax: 4 rows/block, 1 wave/row, no barriers ----------------
__global__ __launch_bounds__(256)
void softmax256(float* __restrict__ x)
{
  const int row = blockIdx.x * 4 + (threadIdx.x >> 6);
  const int l = threadIdx.x & 63;
  float4 v = *(float4*)&x[(long long)row * 256 + l * 4];
  float m = fmaxf(fmaxf(v.x, v.y), fmaxf(v.z, v.w));
  for (int s = 32; s; s >>= 1) m = fmaxf(m, __shfl_xor(m, s));
  float e0 = expf(v.x - m), e1 = expf(v.y - m), e2 = expf(v.z - m), e3 = expf(v.w - m);
  float sm = e0 + e1 + e2 + e3;
  for (int s = 32; s; s >>= 1) sm += __shfl_xor(sm, s);
  float inv = 1.f / sm;
  *(float4*)&x[(long long)row * 256 + l * 4] = make_float4(e0*inv, e1*inv, e2*inv, e3*inv);
}

// ---------------- z = eps*exp(0.5*lv)+mu, fused with KLD row partial ----------------
__global__ __launch_bounds__(256)
void z_kld(const float* __restrict__ eps, const float* __restrict__ mpo,
           const float* __restrict__ mpr, float* __restrict__ z, SelState* st)
{
  __shared__ float red[256];
  const int row = blockIdx.x, c = threadIdx.x;
  float mu = mpo[row * 512 + c], lv = mpo[row * 512 + 256 + c];
  z[row * 256 + c] = eps[row * 256 + c] * expf(0.5f * lv) + mu;
  float mu2 = mpr[row * 512 + c], lv2 = mpr[row * 512 + 256 + c];
  float d = mu2 - mu, dl = lv - lv2;
  red[c] = d * d * expf(-lv2) + expf(dl) - 1.f - dl;
  __syncthreads();
  for (int s = 128; s > 0; s >>= 1) { if (c < s) red[c] += red[c + s]; __syncthreads(); }
  if (c == 0) atomicAdd(&st->kldSum, (double)red[0]);
}

// ---------------- select: fast path (cnt1>=512 -> T=1.0f) else full radix fallback ----------------
__global__ __launch_bounds__(1024)
void select_kernel(const float* __restrict__ radj, SelState* st, unsigned* __restrict__ rowTies)
{
  const int tid = threadIdx.x;
  if (st->cnt1 >= (unsigned)TOPK) {
    if (tid == 0) { st->T = ONEB; st->r = TOPK; }
    return;
  }
  __shared__ unsigned hist[256];
  __shared__ unsigned prefix_s, rem_s;
  unsigned prefix = 0, rem = TOPK;
  for (int pass = 0; pass < 4; ++pass) {
    const int shift = 24 - 8 * pass;
    const unsigned mask = pass ? (0xFFFFFFFFu << (32 - 8 * pass)) : 0u;
    if (tid < 256) hist[tid] = 0;
    __syncthreads();
    for (int idx = tid; idx < TOTE; idx += 1024) {
      int i = idx >> 11, j = idx & 2047;
      if (j <= i) continue;
      unsigned b = __float_as_uint(radj[idx]);
      if ((b & mask) == prefix) atomicAdd(&hist[(b >> shift) & 255], 1u);
    }
    __syncthreads();
    if (tid == 0) {
      unsigned cg = 0;
      for (int bb = 255; bb >= 0; --bb) {
        unsigned c = hist[bb];
        if (cg + c >= rem) { prefix |= ((unsigned)bb) << shift; rem -= cg; break; }
        cg += c;
      }
      prefix_s = prefix; rem_s = rem;
    }
    __syncthreads();
    prefix = prefix_s; rem = rem_s;
  }
  if (tid == 0) { st->T = prefix; st->r = rem; }
  for (int r = tid; r < NN; r += 1024) rowTies[r] = 0;
  __syncthreads();
  for (int idx = tid; idx < TOTE; idx += 1024) {
    int i = idx >> 11, j = idx & 2047;
    if (j <= i) continue;
    if (__float_as_uint(radj[idx]) == prefix) atomicAdd(&rowTies[i], 1u);
  }
}

// ---------------- cut row: prefix-scan rowTies to find row containing the r-th tie ----------------
__global__ __launch_bounds__(256)
void cut_row(const unsigned* __restrict__ rowTies, SelState* st)
{
  __shared__ unsigned ps[256];
  const int t = threadIdx.x;
  unsigned loc[8], s = 0;
  for (int i = 0; i < 8; ++i) { loc[i] = rowTies[t * 8 + i]; s += loc[i]; }
  ps[t] = s; __syncthreads();
  for (int sh = 1; sh < 256; sh <<= 1) {
    unsigned v = (t >= sh) ? ps[t - sh] : 0; __syncthreads();
    ps[t] += v; __syncthreads();
  }
  const unsigned r = st->r;
  const unsigned exc = ps[t] - s;
  if (r > exc && r <= ps[t]) {
    unsigned cum = exc;
    for (int i = 0; i < 8; ++i) {
      if (r <= cum + loc[i]) { st->tieRow = t * 8 + i; st->tieRem = r - cum; break; }
      cum += loc[i];
    }
  }
}

// ---------------- find exact threshold column within the cut row (one wave, ballot) ----------------
__global__ __launch_bounds__(64)
void find_col(const float* __restrict__ radj, SelState* st)
{
  const int R = (int)st->tieRow;
  const unsigned rem = st->tieRem, T = st->T;
  unsigned base = 0;
  for (int c0 = R + 1; c0 < NN; c0 += 64) {
    const int c = c0 + (int)threadIdx.x;
    bool f = (c < NN) && (__float_as_uint(radj[(long long)R * NN + c]) == T);
    unsigned long long m = __ballot(f);
    unsigned cnt = (unsigned)__popcll(m);
    if (base + cnt >= rem) {
      if (f) {
        unsigned rank = (unsigned)__popcll(m & ((1ull << threadIdx.x) - 1ull)) + 1u;
        if (base + rank == rem) st->Ithr = (unsigned)(R * NN + c);
      }
      return;
    }
    base += cnt;
  }
}

__global__ __launch_bounds__(256)
void collect_kernel(const float* __restrict__ radj, SelState* st,
                    unsigned* __restrict__ cand_bits, unsigned* __restrict__ cand_idx)
{
  const int row = blockIdx.x;
  const unsigned T = st->T, It = st->Ithr;
  for (int c = row + 1 + threadIdx.x; c < NN; c += 256) {
    int idx = row * NN + c;
    unsigned b = __float_as_uint(radj[idx]);
    if (b > T || (b == T && (unsigned)idx <= It)) {
      unsigned p = atomicAdd(&st->cTotal, 1u);
      if (p < (unsigned)TOPK) { cand_bits[p] = b; cand_idx[p] = (unsigned)idx; }
    }
  }
}

__global__ __launch_bounds__(512)
void rank_sort(const unsigned* __restrict__ cand_bits,
               const unsigned* __restrict__ cand_idx, unsigned* __restrict__ ord)
{
  __shared__ unsigned vb[512], vi[512];
  const int t = threadIdx.x;
  vb[t] = cand_bits[t]; vi[t] = cand_idx[t];
  __syncthreads();
  unsigned b = vb[t], id = vi[t];
  int rank = 0;
  for (int u = 0; u < 512; ++u)
    rank += (vb[u] > b) || (vb[u] == b && vi[u] < id);
  ord[rank] = id;
}

__global__ __launch_bounds__(256)
void gather_rel(const unsigned* __restrict__ ord, const float* __restrict__ ns2,
                float* __restrict__ out)
{
  const int r = blockIdx.x, c = threadIdx.x;
  unsigned id = ord[r];
  int a = id >> 11, b = id & 2047;
  out[r * 256 + c] = ns2[a * 256 + c] + ns2[b * 256 + c];
}

__global__ __launch_bounds__(512)
void finalize_kernel(const SelState* st, float* __restrict__ out)
{
  const int t = threadIdx.x;
  out[TOPK * H2D + t] = 0.0f;                 // rel_mask: all False
  if (t == 0) {
    double s   = st->labSum;
    double nn  = (double)NN * NN;
    double pw  = (nn - s + NN) / (s - NN + 0.01);
    double nrm = nn / (nn - s + NN);
    out[TOPK * H2D + TOPK + 0] = (float)(nrm * (pw * st->sum1 + st->sum0) / nn);
    out[TOPK * H2D + TOPK + 1] = (float)(0.5 * st->kldSum / nn);
  }
}

} // namespace

extern "C" void kernel_launch(void* const* d_in, const int* in_sizes, int n_in,
                              void* d_out, int out_size, void* d_ws, size_t ws_size,
                              hipStream_t stream)
{
  (void)in_sizes; (void)n_in; (void)out_size; (void)ws_size;
  const float* ns_emb    = (const float*)d_in[0];
  const float* adj       = (const float*)d_in[1];
  const float* adj_prior = (const float*)d_in[2];
  const float* cond      = (const float*)d_in[3];
  const float* labels    = (const float*)d_in[4];
  const float* eps       = (const float*)d_in[5];
  const float* W_map     = (const float*)d_in[6];
  const float* Wb[2][7];
  for (int k = 0; k < 14; ++k) Wb[k / 7][k % 7] = (const float*)d_in[7 + k];
  float* out = (float*)d_out;

  // ---- workspace ----
  char* w = (char*)d_ws;
  SelState* st      = (SelState*)w;          w += 256;
  unsigned* rowTies = (unsigned*)w;          w += NN * 4;     // memset with st
  unsigned* cand_bits = (unsigned*)w;        w += TOPK * 4;
  unsigned* cand_idx  = (unsigned*)w;        w += TOPK * 4;
  unsigned* ord       = (unsigned*)w;        w += TOPK * 4;
  w = (char*)(((uintptr_t)w + 255) & ~(uintptr_t)255);
  int* ellCnt[2]; int* ellCol[2]; float* ellVal[2];
  for (int b = 0; b < 2; ++b) {
    ellCnt[b] = (int*)w;   w += NN * 4;
    ellCol[b] = (int*)w;   w += (size_t)NN * CAP * 4;
    ellVal[b] = (float*)w; w += (size_t)NN * CAP * 4;
  }
  const long long NNH1 = (long long)NN * H1D;
  const long long LCH  = (long long)LCD * H1D;
  float* AR = (float*)w;  w += (size_t)(6 * NNH1 + 4 * LCH) * 4;
  float* mulv[2];
  mulv[0] = (float*)w;    w += (size_t)NNH1 * 4;
  mulv[1] = (float*)w;    w += (size_t)NNH1 * 4;
  float* zb  = (float*)w; w += (size_t)NN * H2D * 4;
  float* ns2 = (float*)w; w += (size_t)NN * H2D * 4;

  // arena aliases (S->Q->H2 share; H->O share; SC->T2 share; radj over all at decode)
  float* S[2]  = { AR,          AR + NNH1 };
  float* Q[2]  = { AR,          AR + NNH1 };
  float* H[2]  = { AR + 2*NNH1, AR + 3*NNH1 };
  float* O[2]  = { AR + 2*NNH1, AR + 3*NNH1 };
  float* Kb[2] = { AR + 4*NNH1,         AR + 4*NNH1 + LCH };
  float* Vb[2] = { AR + 4*NNH1 + 2*LCH, AR + 4*NNH1 + 3*LCH };
  float* SC    =   AR + 4*NNH1 + 4*LCH;
  float* T2[2] = { SC,          SC + NNH1 };
  float* H2[2] = { AR,          AR + NNH1 };
  float* radj  =   AR;

  hipMemsetAsync(st, 0, 256 + NN * 4, stream);   // SelState + rowTies

  { // ELL build
    EB eb{};
    eb.adj[0] = adj; eb.adj[1] = adj_prior;
    for (int b = 0; b < 2; ++b) { eb.cnt[b]=ellCnt[b]; eb.col[b]=ellCol[b]; eb.val[b]=ellVal[b]; }
    build_ell<<<dim3(NN, 2), 64, 0, stream>>>(eb);
  }

  auto mkslot = [](const float* A, const float* B, float* C, int lda, int ldb, int ldc,
                   int nshift, int act, float scale) {
    Slot s; s.A=A; s.B=B; s.C=C; s.lda=lda; s.ldb=ldb; s.ldc=ldc;
    s.nshift=nshift; s.act=act; s.scale=scale; return s;
  };

  { // phase 1: S[2] (leaky), K/V[4], ns2 (leaky) — all K=768 inputs
    Launch P{};
    P.s[0] = mkslot(ns_emb, Wb[0][0], S[0], FIN, H1D, H1D, 3, 1, 1.f);
    P.s[1] = mkslot(ns_emb, Wb[1][0], S[1], FIN, H1D, H1D, 3, 1, 1.f);
    P.s[2] = mkslot(cond,   Wb[0][2], Kb[0], FIN, H1D, H1D, 3, 0, 1.f);
    P.s[3] = mkslot(cond,   Wb[1][2], Kb[1], FIN, H1D, H1D, 3, 0, 1.f);
    P.s[4] = mkslot(cond,   Wb[0][3], Vb[0], FIN, H1D, H1D, 3, 0, 1.f);
    P.s[5] = mkslot(cond,   Wb[1][3], Vb[1], FIN, H1D, H1D, 3, 0, 1.f);
    P.s[6] = mkslot(ns_emb, W_map,    ns2,  FIN, H2D, H2D, 2, 1, 1.f);
    int ze[8] = {256, 512, 544, 576, 608, 640, 768, 768};
    for (int i = 0; i < 8; ++i) P.zend[i] = ze[i];
    mega_gemm<0><<<dim3(768), 256, 0, stream>>>(P, FIN);
  }
  { // spmm1: H = leaky(adj @ S)
    SB sb{};
    for (int br = 0; br < 2; ++br) { sb.cnt[br]=ellCnt[br]; sb.col[br]=ellCol[br];
      sb.val[br]=ellVal[br]; sb.S[br]=S[br]; sb.out[br]=H[br]; }
    spmm_leaky<<<dim3(NN, 2), 256, 0, stream>>>(sb);
  }
  { // Q = H @ Wq
    Launch P{};
    P.s[0] = mkslot(H[0], Wb[0][1], Q[0], H1D, H1D, H1D, 3, 0, 1.f);
    P.s[1] = mkslot(H[1], Wb[1][1], Q[1], H1D, H1D, H1D, 3, 0, 1.f);
    int ze[8] = {256, 512, 512, 512, 512, 512, 512, 512};
    for (int i = 0; i < 8; ++i) P.zend[i] = ze[i];
    mega_gemm<0><<<dim3(512), 256, 0, stream>>>(P, H1D);
  }
  { // scores = Q_hd @ K_hd^T / 16
    Launch P{};
    for (int br = 0; br < 2; ++br) for (int hd = 0; hd < 2; ++hd) {
      int z = br * 2 + hd;
      P.s[z] = mkslot(Q[br] + hd*256, Kb[br] + hd*256, SC + (long long)z*NN*256,
                      H1D, H1D, 256, 2, 0, 0.0625f);
    }
    int ze[8] = {128, 256, 384, 512, 512, 512, 512, 512};
    for (int i = 0; i < 8; ++i) P.zend[i] = ze[i];
    mega_gemm<1><<<dim3(512), 256, 0, stream>>>(P, 256);
  }
  softmax256<<<dim3(NN), 256, 0, stream>>>(SC);
  { // O = attn @ V_hd
    Launch P{};
    for (int br = 0; br < 2; ++br) for (int hd = 0; hd < 2; ++hd) {
      int z = br * 2 + hd;
      P.s[z] = mkslot(SC + (long long)z*NN*256, Vb[br] + hd*256, O[br] + hd*256,
                      256, H1D, H1D, 2, 0, 1.f);
    }
    int ze[8] = {128, 256, 384, 512, 512, 512, 512, 512};
    for (int i = 0; i < 8; ++i) P.zend[i] = ze[i];
    mega_gemm<0><<<dim3(512), 256, 0, stream>>>(P, 256);
  }
  { // H2 = O @ Wo
    Launch P{};
    P.s[0] = mkslot(O[0], Wb[0][4], H2[0], H1D, H1D, H1D, 3, 0, 1.f);
    P.s[1] = mkslot(O[1], Wb[1][4], H2[1], H1D, H1D, H1D, 3, 0, 1.f);
    int ze[8] = {256, 512, 512, 512, 512, 512, 512, 512};
    for (int i = 0; i < 8; ++i) P.zend[i] = ze[i];
    mega_gemm<0><<<dim3(512), 256, 0, stream>>>(P, H1D);
  }
  { // T2 = leaky(H2 @ [Wmu|Wvar])
    Launch P{};
    for (int br = 0; br < 2; ++br) {
      P.s[br]   = mkslot(H2[br], Wb[br][5], T2[br],       H1D, H2D, H1D, 2, 1, 1.f);
      P.s[2+br] = mkslot(H2[br], Wb[br][6], T2[br] + H2D, H1D, H2D, H1D, 2, 1, 1.f);
    }
    int ze[8] = {128, 256, 384, 512, 512, 512, 512, 512};
    for (int i = 0; i < 8; ++i) P.zend[i] = ze[i];
    mega_gemm<0><<<dim3(512), 256, 0, stream>>>(P, H1D);
  }
  { // spmm2: mulv = leaky(adj @ T2)
    SB sb{};
    for (int br = 0; br < 2; ++br) { sb.cnt[br]=ellCnt[br]; sb.col[br]=ellCol[br];
      sb.val[br]=ellVal[br]; sb.S[br]=T2[br]; sb.out[br]=mulv[br]; }
    spmm_leaky<<<dim3(NN, 2), 256, 0, stream>>>(sb);
  }

  z_kld<<<dim3(NN), 256, 0, stream>>>(eps, mulv[0], mulv[1], zb, st);
  zzt_fused<<<dim3(32, 32), 256, 0, stream>>>(zb, labels, radj, st, rowTies);

  select_kernel<<<dim3(1), 1024, 0, stream>>>(radj, st, rowTies);
  cut_row<<<dim3(1), 256, 0, stream>>>(rowTies, st);
  find_col<<<dim3(1), 64, 0, stream>>>(radj, st);
  collect_kernel<<<dim3(NN), 256, 0, stream>>>(radj, st, cand_bits, cand_idx);
  rank_sort<<<dim3(1), 512, 0, stream>>>(cand_bits, cand_idx, ord);
  gather_rel<<<dim3(TOPK), 256, 0, stream>>>(ord, ns2, out);
  finalize_kernel<<<dim3(1), 512, 0, stream>>>(st, out);
}